// Round 2
// baseline (366.202 us; speedup 1.0000x reference)
//
#include <hip/hip_runtime.h>

#define HW_  16384   // H*W = 128*128
#define NPX  32768   // B*H*W

__device__ __forceinline__ float prelu_(float x, float a) { return x >= 0.f ? x : a * x; }

// ---------------- K1: x1 = prelu(conv1x1(x, w1, b1), a1) ----------------
// 4 output-channel splits x 16 out/thread; streaming over 128 input channels.
__global__ __launch_bounds__(256) void k_conv1(const float* __restrict__ x,
        const float* __restrict__ w1, const float* __restrict__ b1,
        const float* __restrict__ a1p, float* __restrict__ x1) {
    int tid = blockIdx.x * 256 + threadIdx.x;
    int px = tid & (NPX - 1);
    int q = tid >> 15;               // 0..3, block-uniform
    int b = px >> 14, hw = px & (HW_ - 1);
    int o0 = q * 16;
    const float a1 = a1p[0];
    float acc[16];
    #pragma unroll
    for (int u = 0; u < 16; ++u) acc[u] = b1[o0 + u];
    const float* xp = x + (b << 21) + hw;           // b*128*HW_
    #pragma unroll 4
    for (int c = 0; c < 128; ++c) {
        float xv = xp[c << 14];
        #pragma unroll
        for (int u = 0; u < 16; ++u)
            acc[u] = fmaf(w1[(o0 + u) * 128 + c], xv, acc[u]);
    }
    float* op = x1 + (b << 20) + hw;                // b*64*HW_
    #pragma unroll
    for (int u = 0; u < 16; ++u) op[(o0 + u) << 14] = prelu_(acc[u], a1);
}

// ---------------- K2: f = relu(conv1x1(x1, wr, br)) ----------------
// 2 splits x 16 out/thread; streaming over 64 input channels.
__global__ __launch_bounds__(256) void k_reduce(const float* __restrict__ x1,
        const float* __restrict__ wr, const float* __restrict__ br,
        float* __restrict__ f) {
    int tid = blockIdx.x * 256 + threadIdx.x;
    int px = tid & (NPX - 1);
    int half = tid >> 15;            // 0..1, block-uniform
    int b = px >> 14, hw = px & (HW_ - 1);
    int o0 = half * 16;
    float acc[16];
    #pragma unroll
    for (int u = 0; u < 16; ++u) acc[u] = br[o0 + u];
    const float* xp = x1 + (b << 20) + hw;
    #pragma unroll 4
    for (int c = 0; c < 64; ++c) {
        float xv = xp[c << 14];
        #pragma unroll
        for (int u = 0; u < 16; ++u)
            acc[u] = fmaf(wr[(o0 + u) * 64 + c], xv, acc[u]);
    }
    float* op = f + (b << 19) + hw;                 // b*32*HW_
    #pragma unroll
    for (int u = 0; u < 16; ++u) op[(o0 + u) << 14] = fmaxf(acc[u], 0.f);
}

// ---------------- K3: fused span conv + involution -> x2 (+ ZPool for g==0) ----
__global__ __launch_bounds__(256) void k_invol(const float* __restrict__ x1,
        const float* __restrict__ f, const float* __restrict__ ws_,
        const float* __restrict__ bs, float* __restrict__ x2,
        float* __restrict__ zp) {
    int tid = blockIdx.x * 256 + threadIdx.x;
    int px = tid & (NPX - 1);
    int g = tid >> 15;               // 0..3, block-uniform
    int b = px >> 14, hw = px & (HW_ - 1);
    int h = hw >> 7, w = hw & 127;
    float fv[32];
    const float* fp = f + (b << 19) + hw;
    #pragma unroll
    for (int c = 0; c < 32; ++c) fv[c] = fp[c << 14];
    if (g == 0) {                    // block-uniform branch: free ZPool
        float mx = fv[0], sm = fv[0];
        #pragma unroll
        for (int c = 1; c < 32; ++c) { mx = fmaxf(mx, fv[c]); sm += fv[c]; }
        zp[((b * 2 + 0) << 14) + hw] = mx;
        zp[((b * 2 + 1) << 14) + hw] = sm * (1.f / 32.f);
    }
    float acc[16];
    #pragma unroll
    for (int u = 0; u < 16; ++u) acc[u] = 0.f;
    const float* x1p = x1 + ((b * 64 + g * 16) << 14);
    for (int kk = 0; kk < 49; ++kk) {
        int o = g * 49 + kk;
        float kwv = bs[o];
        #pragma unroll
        for (int c = 0; c < 32; ++c) kwv = fmaf(ws_[o * 32 + c], fv[c], kwv);
        int hh = h + (kk / 7) - 3;
        int ww = w + (kk % 7) - 3;
        if (hh >= 0 && hh < 128 && ww >= 0 && ww < 128) {
            int base = (hh << 7) + ww;
            #pragma unroll
            for (int u = 0; u < 16; ++u)
                acc[u] = fmaf(kwv, x1p[base + (u << 14)], acc[u]);
        }
    }
    float* op = x2 + ((b * 64 + g * 16) << 14) + hw;
    #pragma unroll
    for (int u = 0; u < 16; ++u) op[u << 14] = acc[u];
}

// ---------------- K4: attn = sigmoid(conv7x7(zp, wa, ba)) ----------------
__global__ __launch_bounds__(64) void k_attn(const float* __restrict__ zp,
        const float* __restrict__ wa, const float* __restrict__ ba,
        float* __restrict__ attn) {
    int px = blockIdx.x * 64 + threadIdx.x;
    int b = px >> 14, hw = px & (HW_ - 1);
    int h = hw >> 7, w = hw & 127;
    float acc = ba[0];
    for (int c = 0; c < 2; ++c)
        for (int i = 0; i < 7; ++i) {
            int hh = h + i - 3;
            if (hh < 0 || hh >= 128) continue;
            #pragma unroll
            for (int j = 0; j < 7; ++j) {
                int ww = w + j - 3;
                if (ww < 0 || ww >= 128) continue;
                acc = fmaf(wa[c * 49 + i * 7 + j],
                           zp[((b * 2 + c) << 14) + (hh << 7) + ww], acc);
            }
        }
    attn[px] = 1.f / (1.f + expf(-acc));
}

// ---------------- K5: p1 = prelu(conv3x3(f, wp1, bp1), ap) ----------------
// 2 splits x 16 out/thread.
__global__ __launch_bounds__(256) void k_psec1(const float* __restrict__ f,
        const float* __restrict__ wp1, const float* __restrict__ bp1,
        const float* __restrict__ app, float* __restrict__ p1) {
    int tid = blockIdx.x * 256 + threadIdx.x;
    int px = tid & (NPX - 1);
    int half = tid >> 15;            // 0..1, block-uniform
    int b = px >> 14, hw = px & (HW_ - 1);
    int h = hw >> 7, w = hw & 127;
    int o0 = half * 16;
    const float ap = app[0];
    float acc[16];
    #pragma unroll
    for (int u = 0; u < 16; ++u) acc[u] = bp1[o0 + u];
    const float* fp = f + (b << 19);
    for (int ci = 0; ci < 32; ++ci) {
        const float* fc = fp + (ci << 14);
        #pragma unroll
        for (int i = 0; i < 3; ++i) {
            int hh = h + i - 1;
            if (hh < 0 || hh >= 128) continue;
            #pragma unroll
            for (int j = 0; j < 3; ++j) {
                int ww = w + j - 1;
                if (ww < 0 || ww >= 128) continue;
                float v = fc[(hh << 7) + ww];
                #pragma unroll
                for (int u = 0; u < 16; ++u)
                    acc[u] = fmaf(wp1[((o0 + u) * 32 + ci) * 9 + i * 3 + j], v, acc[u]);
            }
        }
    }
    float* op = p1 + (b << 19) + hw;
    #pragma unroll
    for (int u = 0; u < 16; ++u) op[(o0 + u) << 14] = prelu_(acc[u], ap);
}

// ---------------- K6: out = conv2(prelu(x2,a2))*attn + (wp2·p1+bp2) --------
// 8 splits x 16 out/thread; streaming.
__global__ __launch_bounds__(256) void k_final(const float* __restrict__ x2,
        const float* __restrict__ p1, const float* __restrict__ attn,
        const float* __restrict__ a2p, const float* __restrict__ w2,
        const float* __restrict__ b2, const float* __restrict__ wp2,
        const float* __restrict__ bp2, float* __restrict__ out) {
    int tid = blockIdx.x * 256 + threadIdx.x;
    int px = tid & (NPX - 1);
    int q = tid >> 15;               // 0..7, block-uniform
    int b = px >> 14, hw = px & (HW_ - 1);
    int o0 = q * 16;
    const float a2 = a2p[0];
    float acc[16];
    #pragma unroll
    for (int u = 0; u < 16; ++u) acc[u] = b2[o0 + u];
    const float* xp = x2 + (b << 20) + hw;
    #pragma unroll 4
    for (int c = 0; c < 64; ++c) {
        float xv = prelu_(xp[c << 14], a2);
        #pragma unroll
        for (int u = 0; u < 16; ++u)
            acc[u] = fmaf(w2[(o0 + u) * 64 + c], xv, acc[u]);
    }
    float at = attn[px];
    #pragma unroll
    for (int u = 0; u < 16; ++u) acc[u] = acc[u] * at + bp2[o0 + u];
    const float* pp = p1 + (b << 19) + hw;
    #pragma unroll 4
    for (int c = 0; c < 32; ++c) {
        float pv = pp[c << 14];
        #pragma unroll
        for (int u = 0; u < 16; ++u)
            acc[u] = fmaf(wp2[(o0 + u) * 32 + c], pv, acc[u]);
    }
    float* op = out + ((b * 128 + o0) << 14) + hw;
    #pragma unroll
    for (int u = 0; u < 16; ++u) op[u << 14] = acc[u];
}

extern "C" void kernel_launch(void* const* d_in, const int* in_sizes, int n_in,
                              void* d_out, int out_size, void* d_ws, size_t ws_size,
                              hipStream_t stream) {
    const float* x   = (const float*)d_in[0];
    const float* w1  = (const float*)d_in[1];
    const float* b1  = (const float*)d_in[2];
    const float* a1  = (const float*)d_in[3];
    const float* wr  = (const float*)d_in[4];
    const float* br  = (const float*)d_in[5];
    const float* ws_ = (const float*)d_in[6];
    const float* bs  = (const float*)d_in[7];
    const float* a2  = (const float*)d_in[8];
    const float* w2  = (const float*)d_in[9];
    const float* b2  = (const float*)d_in[10];
    const float* wa  = (const float*)d_in[11];
    const float* ba  = (const float*)d_in[12];
    const float* wp1 = (const float*)d_in[13];
    const float* bp1 = (const float*)d_in[14];
    const float* ap  = (const float*)d_in[15];
    const float* wp2 = (const float*)d_in[16];
    const float* bp2 = (const float*)d_in[17];
    float* out = (float*)d_out;

    float* w = (float*)d_ws;
    float* ws_x1   = w;                        // 2*64*HW_
    float* ws_f    = ws_x1 + 2 * 64 * HW_;     // 2*32*HW_
    float* ws_x2   = ws_f  + 2 * 32 * HW_;     // 2*64*HW_
    float* ws_zp   = ws_x2 + 2 * 64 * HW_;     // 2*2*HW_
    float* ws_attn = ws_zp + 2 * 2 * HW_;      // NPX
    float* ws_p1   = ws_attn + NPX;            // 2*32*HW_

    hipLaunchKernelGGL(k_conv1, dim3(4 * NPX / 256), dim3(256), 0, stream,
                       x, w1, b1, a1, ws_x1);
    hipLaunchKernelGGL(k_reduce, dim3(2 * NPX / 256), dim3(256), 0, stream,
                       ws_x1, wr, br, ws_f);
    hipLaunchKernelGGL(k_invol, dim3(4 * NPX / 256), dim3(256), 0, stream,
                       ws_x1, ws_f, ws_, bs, ws_x2, ws_zp);
    hipLaunchKernelGGL(k_attn, dim3(NPX / 64), dim3(64), 0, stream,
                       ws_zp, wa, ba, ws_attn);
    hipLaunchKernelGGL(k_psec1, dim3(2 * NPX / 256), dim3(256), 0, stream,
                       ws_f, wp1, bp1, ap, ws_p1);
    hipLaunchKernelGGL(k_final, dim3(8 * NPX / 256), dim3(256), 0, stream,
                       ws_x2, ws_p1, ws_attn, a2, w2, b2, wp2, bp2, out);
}

// Round 3
// 337.143 us; speedup vs baseline: 1.0862x; 1.0862x over previous
//
#include <hip/hip_runtime.h>

#define HW_  16384   // H*W = 128*128
#define NPX  32768   // B*H*W

__device__ __forceinline__ float prelu_(float x, float a) { return x >= 0.f ? x : a * x; }

// ---------------- K1: x1 = prelu(conv1x1(x, w1, b1), a1) ----------------
// 8 output-channel splits x 8 out/thread; streaming over 128 input channels.
__global__ __launch_bounds__(256) void k_conv1(const float* __restrict__ x,
        const float* __restrict__ w1, const float* __restrict__ b1,
        const float* __restrict__ a1p, float* __restrict__ x1) {
    int tid = blockIdx.x * 256 + threadIdx.x;
    int px = tid & (NPX - 1);
    int q = tid >> 15;               // 0..7, block-uniform
    int b = px >> 14, hw = px & (HW_ - 1);
    int o0 = q * 8;
    const float a1 = a1p[0];
    float acc[8];
    #pragma unroll
    for (int u = 0; u < 8; ++u) acc[u] = b1[o0 + u];
    const float* xp = x + (b << 21) + hw;           // b*128*HW_
    #pragma unroll 8
    for (int c = 0; c < 128; ++c) {
        float xv = xp[c << 14];
        #pragma unroll
        for (int u = 0; u < 8; ++u)
            acc[u] = fmaf(w1[(o0 + u) * 128 + c], xv, acc[u]);
    }
    float* op = x1 + (b << 20) + hw;                // b*64*HW_
    #pragma unroll
    for (int u = 0; u < 8; ++u) op[(o0 + u) << 14] = prelu_(acc[u], a1);
}

// ---------------- K2: f = relu(conv1x1(x1, wr, br)) ----------------
// 4 splits x 8 out/thread.
__global__ __launch_bounds__(256) void k_reduce(const float* __restrict__ x1,
        const float* __restrict__ wr, const float* __restrict__ br,
        float* __restrict__ f) {
    int tid = blockIdx.x * 256 + threadIdx.x;
    int px = tid & (NPX - 1);
    int q = tid >> 15;               // 0..3, block-uniform
    int b = px >> 14, hw = px & (HW_ - 1);
    int o0 = q * 8;
    float acc[8];
    #pragma unroll
    for (int u = 0; u < 8; ++u) acc[u] = br[o0 + u];
    const float* xp = x1 + (b << 20) + hw;
    #pragma unroll 8
    for (int c = 0; c < 64; ++c) {
        float xv = xp[c << 14];
        #pragma unroll
        for (int u = 0; u < 8; ++u)
            acc[u] = fmaf(wr[(o0 + u) * 64 + c], xv, acc[u]);
    }
    float* op = f + (b << 19) + hw;                 // b*32*HW_
    #pragma unroll
    for (int u = 0; u < 8; ++u) op[(o0 + u) << 14] = fmaxf(acc[u], 0.f);
}

// ---------------- K3: fused span conv + involution -> x2 (+ ZPool on g==0) ----
// One block = one group g x one 16x16 pixel tile. x1 halo staged in LDS.
__global__ __launch_bounds__(256) void k_invol(const float* __restrict__ x1,
        const float* __restrict__ f, const float* __restrict__ ws_,
        const float* __restrict__ bs, float* __restrict__ x2,
        float* __restrict__ zp) {
    __shared__ float tile[16 * 22 * 24];   // [c][r][col], rowstride 24 (2-way bank alias = free)
    int g = blockIdx.x >> 7;               // 0..3, block-uniform
    int t = blockIdx.x & 127;              // b*64 + tile id
    int b = t >> 6;
    int th = (t >> 3) & 7, tw = t & 7;
    int h0 = th * 16, w0 = tw * 16;
    const float* x1g = x1 + ((b * 64 + g * 16) << 14);
    for (int e = threadIdx.x; e < 16 * 484; e += 256) {
        int c = e / 484;
        int rem = e - c * 484;
        int r = rem / 22, cl = rem - r * 22;
        int hh = h0 + r - 3, ww = w0 + cl - 3;
        float v = 0.f;
        if (hh >= 0 && hh < 128 && ww >= 0 && ww < 128)
            v = x1g[(c << 14) + (hh << 7) + ww];
        tile[c * 528 + r * 24 + cl] = v;
    }
    int lh = threadIdx.x >> 4, lw = threadIdx.x & 15;
    int hw = ((h0 + lh) << 7) + w0 + lw;
    float fv[32];
    const float* fp = f + (b << 19) + hw;
    #pragma unroll
    for (int c = 0; c < 32; ++c) fv[c] = fp[c << 14];
    if (g == 0) {                          // block-uniform: free ZPool
        float mx = fv[0], sm = fv[0];
        #pragma unroll
        for (int c = 1; c < 32; ++c) { mx = fmaxf(mx, fv[c]); sm += fv[c]; }
        zp[((b * 2 + 0) << 14) + hw] = mx;
        zp[((b * 2 + 1) << 14) + hw] = sm * (1.f / 32.f);
    }
    __syncthreads();
    float acc[16];
    #pragma unroll
    for (int u = 0; u < 16; ++u) acc[u] = 0.f;
    const float* tap0 = tile + lh * 24 + lw;
    const float* wk = ws_ + g * 49 * 32;
    const float* bsg = bs + g * 49;
    #pragma unroll 1
    for (int di = 0; di < 7; ++di) {
        #pragma unroll 1
        for (int dj = 0; dj < 7; ++dj) {
            int kk = di * 7 + dj;
            float kwv = bsg[kk];
            const float* wkk = wk + kk * 32;
            #pragma unroll
            for (int c = 0; c < 32; ++c) kwv = fmaf(wkk[c], fv[c], kwv);
            const float* tp = tap0 + di * 24 + dj;
            #pragma unroll
            for (int u = 0; u < 16; ++u)
                acc[u] = fmaf(kwv, tp[u * 528], acc[u]);
        }
    }
    float* op = x2 + ((b * 64 + g * 16) << 14) + hw;
    #pragma unroll
    for (int u = 0; u < 16; ++u) op[u << 14] = acc[u];
}

// ---------------- K4: attn = sigmoid(conv7x7(zp, wa, ba)) ----------------
__global__ __launch_bounds__(64) void k_attn(const float* __restrict__ zp,
        const float* __restrict__ wa, const float* __restrict__ ba,
        float* __restrict__ attn) {
    int px = blockIdx.x * 64 + threadIdx.x;
    int b = px >> 14, hw = px & (HW_ - 1);
    int h = hw >> 7, w = hw & 127;
    float acc = ba[0];
    for (int c = 0; c < 2; ++c)
        for (int i = 0; i < 7; ++i) {
            int hh = h + i - 3;
            if (hh < 0 || hh >= 128) continue;
            #pragma unroll
            for (int j = 0; j < 7; ++j) {
                int ww = w + j - 3;
                if (ww < 0 || ww >= 128) continue;
                acc = fmaf(wa[c * 49 + i * 7 + j],
                           zp[((b * 2 + c) << 14) + (hh << 7) + ww], acc);
            }
        }
    attn[px] = 1.f / (1.f + expf(-acc));
}

// ---------------- K5: p1 = prelu(conv3x3(f, wp1, bp1), ap) ----------------
__global__ __launch_bounds__(256) void k_psec1(const float* __restrict__ f,
        const float* __restrict__ wp1, const float* __restrict__ bp1,
        const float* __restrict__ app, float* __restrict__ p1) {
    int tid = blockIdx.x * 256 + threadIdx.x;
    int px = tid & (NPX - 1);
    int half = tid >> 15;            // 0..1, block-uniform
    int b = px >> 14, hw = px & (HW_ - 1);
    int h = hw >> 7, w = hw & 127;
    int o0 = half * 16;
    const float ap = app[0];
    float acc[16];
    #pragma unroll
    for (int u = 0; u < 16; ++u) acc[u] = bp1[o0 + u];
    const float* fp = f + (b << 19);
    for (int ci = 0; ci < 32; ++ci) {
        const float* fc = fp + (ci << 14);
        #pragma unroll
        for (int i = 0; i < 3; ++i) {
            int hh = h + i - 1;
            if (hh < 0 || hh >= 128) continue;
            #pragma unroll
            for (int j = 0; j < 3; ++j) {
                int ww = w + j - 1;
                if (ww < 0 || ww >= 128) continue;
                float v = fc[(hh << 7) + ww];
                #pragma unroll
                for (int u = 0; u < 16; ++u)
                    acc[u] = fmaf(wp1[((o0 + u) * 32 + ci) * 9 + i * 3 + j], v, acc[u]);
            }
        }
    }
    float* op = p1 + (b << 19) + hw;
    #pragma unroll
    for (int u = 0; u < 16; ++u) op[(o0 + u) << 14] = prelu_(acc[u], ap);
}

// ---------------- K6: out = conv2(prelu(x2,a2))*attn + (wp2·p1+bp2) --------
__global__ __launch_bounds__(256) void k_final(const float* __restrict__ x2,
        const float* __restrict__ p1, const float* __restrict__ attn,
        const float* __restrict__ a2p, const float* __restrict__ w2,
        const float* __restrict__ b2, const float* __restrict__ wp2,
        const float* __restrict__ bp2, float* __restrict__ out) {
    int tid = blockIdx.x * 256 + threadIdx.x;
    int px = tid & (NPX - 1);
    int q = tid >> 15;               // 0..7, block-uniform
    int b = px >> 14, hw = px & (HW_ - 1);
    int o0 = q * 16;
    const float a2 = a2p[0];
    float acc[16];
    #pragma unroll
    for (int u = 0; u < 16; ++u) acc[u] = b2[o0 + u];
    const float* xp = x2 + (b << 20) + hw;
    #pragma unroll 8
    for (int c = 0; c < 64; ++c) {
        float xv = prelu_(xp[c << 14], a2);
        #pragma unroll
        for (int u = 0; u < 16; ++u)
            acc[u] = fmaf(w2[(o0 + u) * 64 + c], xv, acc[u]);
    }
    float at = attn[px];
    #pragma unroll
    for (int u = 0; u < 16; ++u) acc[u] = acc[u] * at + bp2[o0 + u];
    const float* pp = p1 + (b << 19) + hw;
    #pragma unroll 8
    for (int c = 0; c < 32; ++c) {
        float pv = pp[c << 14];
        #pragma unroll
        for (int u = 0; u < 16; ++u)
            acc[u] = fmaf(wp2[(o0 + u) * 32 + c], pv, acc[u]);
    }
    float* op = out + ((b * 128 + o0) << 14) + hw;
    #pragma unroll
    for (int u = 0; u < 16; ++u) op[u << 14] = acc[u];
}

extern "C" void kernel_launch(void* const* d_in, const int* in_sizes, int n_in,
                              void* d_out, int out_size, void* d_ws, size_t ws_size,
                              hipStream_t stream) {
    const float* x   = (const float*)d_in[0];
    const float* w1  = (const float*)d_in[1];
    const float* b1  = (const float*)d_in[2];
    const float* a1  = (const float*)d_in[3];
    const float* wr  = (const float*)d_in[4];
    const float* br  = (const float*)d_in[5];
    const float* ws_ = (const float*)d_in[6];
    const float* bs  = (const float*)d_in[7];
    const float* a2  = (const float*)d_in[8];
    const float* w2  = (const float*)d_in[9];
    const float* b2  = (const float*)d_in[10];
    const float* wa  = (const float*)d_in[11];
    const float* ba  = (const float*)d_in[12];
    const float* wp1 = (const float*)d_in[13];
    const float* bp1 = (const float*)d_in[14];
    const float* ap  = (const float*)d_in[15];
    const float* wp2 = (const float*)d_in[16];
    const float* bp2 = (const float*)d_in[17];
    float* out = (float*)d_out;

    float* w = (float*)d_ws;
    float* ws_x1   = w;                        // 2*64*HW_
    float* ws_f    = ws_x1 + 2 * 64 * HW_;     // 2*32*HW_
    float* ws_x2   = ws_f  + 2 * 32 * HW_;     // 2*64*HW_
    float* ws_zp   = ws_x2 + 2 * 64 * HW_;     // 2*2*HW_
    float* ws_attn = ws_zp + 2 * 2 * HW_;      // NPX
    float* ws_p1   = ws_attn + NPX;            // 2*32*HW_

    hipLaunchKernelGGL(k_conv1, dim3(8 * NPX / 256), dim3(256), 0, stream,
                       x, w1, b1, a1, ws_x1);
    hipLaunchKernelGGL(k_reduce, dim3(4 * NPX / 256), dim3(256), 0, stream,
                       ws_x1, wr, br, ws_f);
    hipLaunchKernelGGL(k_invol, dim3(512), dim3(256), 0, stream,
                       ws_x1, ws_f, ws_, bs, ws_x2, ws_zp);
    hipLaunchKernelGGL(k_attn, dim3(NPX / 64), dim3(64), 0, stream,
                       ws_zp, wa, ba, ws_attn);
    hipLaunchKernelGGL(k_psec1, dim3(2 * NPX / 256), dim3(256), 0, stream,
                       ws_f, wp1, bp1, ap, ws_p1);
    hipLaunchKernelGGL(k_final, dim3(8 * NPX / 256), dim3(256), 0, stream,
                       ws_x2, ws_p1, ws_attn, a2, w2, b2, wp2, bp2, out);
}

// Round 4
// 302.632 us; speedup vs baseline: 1.2101x; 1.1140x over previous
//
#include <hip/hip_runtime.h>

#define HW_  16384   // H*W = 128*128
#define NPX  32768   // B*H*W
#define NPG  8192    // NPX/4 pixel-groups

__device__ __forceinline__ float prelu_(float x, float a) { return x >= 0.f ? x : a * x; }

// ---------------- K1: x1 = prelu(conv1x1(x, w1, b1), a1) ----------------
// 8 output-channel splits x 8 out/thread x 4 px/thread (float4 loads).
__global__ __launch_bounds__(256) void k_conv1(const float* __restrict__ x,
        const float* __restrict__ w1, const float* __restrict__ b1,
        const float* __restrict__ a1p, float* __restrict__ x1) {
    int tid = blockIdx.x * 256 + threadIdx.x;
    int pg = tid & (NPG - 1);
    int q = tid >> 13;               // 0..7, block-uniform
    int b = pg >> 12;
    int hw = (pg & 4095) << 2;
    int o0 = q * 8;
    const float a1 = a1p[0];
    float4 acc[8];
    #pragma unroll
    for (int u = 0; u < 8; ++u) { float bv = b1[o0 + u]; acc[u] = make_float4(bv, bv, bv, bv); }
    const float4* xp = (const float4*)(x + (b << 21) + hw);   // ch stride 4096 float4
    #pragma unroll 8
    for (int c = 0; c < 128; ++c) {
        float4 xv = xp[c << 12];
        #pragma unroll
        for (int u = 0; u < 8; ++u) {
            float wv = w1[(o0 + u) * 128 + c];
            acc[u].x = fmaf(wv, xv.x, acc[u].x);
            acc[u].y = fmaf(wv, xv.y, acc[u].y);
            acc[u].z = fmaf(wv, xv.z, acc[u].z);
            acc[u].w = fmaf(wv, xv.w, acc[u].w);
        }
    }
    float4* op = (float4*)(x1 + (b << 20) + hw);
    #pragma unroll
    for (int u = 0; u < 8; ++u) {
        float4 r;
        r.x = prelu_(acc[u].x, a1); r.y = prelu_(acc[u].y, a1);
        r.z = prelu_(acc[u].z, a1); r.w = prelu_(acc[u].w, a1);
        op[(o0 + u) << 12] = r;
    }
}

// ---------------- K2: f = relu(conv1x1(x1, wr, br)) ----------------
// 4 splits x 8 out/thread x 4 px/thread; 128-thread blocks for grid size.
__global__ __launch_bounds__(128) void k_reduce(const float* __restrict__ x1,
        const float* __restrict__ wr, const float* __restrict__ br,
        float* __restrict__ f) {
    int tid = blockIdx.x * 128 + threadIdx.x;
    int pg = tid & (NPG - 1);
    int q = tid >> 13;               // 0..3, block-uniform
    int b = pg >> 12;
    int hw = (pg & 4095) << 2;
    int o0 = q * 8;
    float4 acc[8];
    #pragma unroll
    for (int u = 0; u < 8; ++u) { float bv = br[o0 + u]; acc[u] = make_float4(bv, bv, bv, bv); }
    const float4* xp = (const float4*)(x1 + (b << 20) + hw);
    #pragma unroll 8
    for (int c = 0; c < 64; ++c) {
        float4 xv = xp[c << 12];
        #pragma unroll
        for (int u = 0; u < 8; ++u) {
            float wv = wr[(o0 + u) * 64 + c];
            acc[u].x = fmaf(wv, xv.x, acc[u].x);
            acc[u].y = fmaf(wv, xv.y, acc[u].y);
            acc[u].z = fmaf(wv, xv.z, acc[u].z);
            acc[u].w = fmaf(wv, xv.w, acc[u].w);
        }
    }
    float4* op = (float4*)(f + (b << 19) + hw);
    #pragma unroll
    for (int u = 0; u < 8; ++u) {
        float4 r;
        r.x = fmaxf(acc[u].x, 0.f); r.y = fmaxf(acc[u].y, 0.f);
        r.z = fmaxf(acc[u].z, 0.f); r.w = fmaxf(acc[u].w, 0.f);
        op[(o0 + u) << 12] = r;
    }
}

// ---------------- K3: fused span conv + involution -> x2 (+ ZPool on g==0) ----
// One block = one group g x one 16x16 pixel tile. x1 halo staged in LDS.
__global__ __launch_bounds__(256) void k_invol(const float* __restrict__ x1,
        const float* __restrict__ f, const float* __restrict__ ws_,
        const float* __restrict__ bs, float* __restrict__ x2,
        float* __restrict__ zp) {
    __shared__ float tile[16 * 22 * 24];   // [c][r][col], rowstride 24 (2-way alias = free)
    int g = blockIdx.x >> 7;               // 0..3, block-uniform
    int t = blockIdx.x & 127;              // b*64 + tile id
    int b = t >> 6;
    int th = (t >> 3) & 7, tw = t & 7;
    int h0 = th * 16, w0 = tw * 16;
    const float* x1g = x1 + ((b * 64 + g * 16) << 14);
    for (int e = threadIdx.x; e < 16 * 484; e += 256) {
        int c = e / 484;
        int rem = e - c * 484;
        int r = rem / 22, cl = rem - r * 22;
        int hh = h0 + r - 3, ww = w0 + cl - 3;
        float v = 0.f;
        if (hh >= 0 && hh < 128 && ww >= 0 && ww < 128)
            v = x1g[(c << 14) + (hh << 7) + cl + w0 - 3 - (cl + w0 - 3) + ww];
        tile[c * 528 + r * 24 + cl] = v;
    }
    int lh = threadIdx.x >> 4, lw = threadIdx.x & 15;
    int hw = ((h0 + lh) << 7) + w0 + lw;
    float fv[32];
    const float* fp = f + (b << 19) + hw;
    #pragma unroll
    for (int c = 0; c < 32; ++c) fv[c] = fp[c << 14];
    if (g == 0) {                          // block-uniform: free ZPool
        float mx = fv[0], sm = fv[0];
        #pragma unroll
        for (int c = 1; c < 32; ++c) { mx = fmaxf(mx, fv[c]); sm += fv[c]; }
        zp[((b * 2 + 0) << 14) + hw] = mx;
        zp[((b * 2 + 1) << 14) + hw] = sm * (1.f / 32.f);
    }
    __syncthreads();
    float acc[16];
    #pragma unroll
    for (int u = 0; u < 16; ++u) acc[u] = 0.f;
    const float* tap0 = tile + lh * 24 + lw;
    const float* wk = ws_ + g * 49 * 32;
    const float* bsg = bs + g * 49;
    #pragma unroll 1
    for (int di = 0; di < 7; ++di) {
        #pragma unroll 1
        for (int dj = 0; dj < 7; ++dj) {
            int kk = di * 7 + dj;
            float kwv = bsg[kk];
            const float* wkk = wk + kk * 32;
            #pragma unroll
            for (int c = 0; c < 32; ++c) kwv = fmaf(wkk[c], fv[c], kwv);
            const float* tp = tap0 + di * 24 + dj;
            #pragma unroll
            for (int u = 0; u < 16; ++u)
                acc[u] = fmaf(kwv, tp[u * 528], acc[u]);
        }
    }
    float* op = x2 + ((b * 64 + g * 16) << 14) + hw;
    #pragma unroll
    for (int u = 0; u < 16; ++u) op[u << 14] = acc[u];
}

// ---------------- K4: attn = sigmoid(conv7x7(zp, wa, ba)) ----------------
__global__ __launch_bounds__(64) void k_attn(const float* __restrict__ zp,
        const float* __restrict__ wa, const float* __restrict__ ba,
        float* __restrict__ attn) {
    int px = blockIdx.x * 64 + threadIdx.x;
    int b = px >> 14, hw = px & (HW_ - 1);
    int h = hw >> 7, w = hw & 127;
    float acc = ba[0];
    for (int c = 0; c < 2; ++c)
        for (int i = 0; i < 7; ++i) {
            int hh = h + i - 3;
            if (hh < 0 || hh >= 128) continue;
            #pragma unroll
            for (int j = 0; j < 7; ++j) {
                int ww = w + j - 3;
                if (ww < 0 || ww >= 128) continue;
                acc = fmaf(wa[c * 49 + i * 7 + j],
                           zp[((b * 2 + c) << 14) + (hh << 7) + ww], acc);
            }
        }
    attn[px] = 1.f / (1.f + expf(-acc));
}

// ---------------- K5: p1 = prelu(conv3x3(f, wp1, bp1), ap) ----------------
// One block = one 16x16 px tile; f halo (32ch x 18x18) staged in LDS; 2 splits.
__global__ __launch_bounds__(256) void k_psec1(const float* __restrict__ f,
        const float* __restrict__ wp1, const float* __restrict__ bp1,
        const float* __restrict__ app, float* __restrict__ p1) {
    __shared__ float fs[32 * 18 * 24];     // [ci][r][col], rowstride 24 = 55 KB
    int half = blockIdx.x >> 7;            // 0..1, block-uniform
    int t = blockIdx.x & 127;
    int b = t >> 6;
    int th = (t >> 3) & 7, tw = t & 7;
    int h0 = th * 16, w0 = tw * 16;
    int o0 = half * 16;
    const float ap = app[0];
    const float* fb = f + (b << 19);
    for (int ci = 0; ci < 32; ++ci) {
        const float* fc = fb + (ci << 14);
        for (int e = threadIdx.x; e < 324; e += 256) {
            int r = e / 18, cl = e - r * 18;
            int hh = h0 + r - 1, ww = w0 + cl - 1;
            float v = 0.f;
            if (hh >= 0 && hh < 128 && ww >= 0 && ww < 128)
                v = fc[(hh << 7) + ww];
            fs[ci * 432 + r * 24 + cl] = v;
        }
    }
    __syncthreads();
    int lh = threadIdx.x >> 4, lw = threadIdx.x & 15;
    float acc[16];
    #pragma unroll
    for (int u = 0; u < 16; ++u) acc[u] = bp1[o0 + u];
    const float* base0 = fs + lh * 24 + lw;
    for (int ci = 0; ci < 32; ++ci) {
        const float* base = base0 + ci * 432;
        float v[9];
        #pragma unroll
        for (int i = 0; i < 3; ++i)
            #pragma unroll
            for (int j = 0; j < 3; ++j)
                v[i * 3 + j] = base[i * 24 + j];
        #pragma unroll
        for (int u = 0; u < 16; ++u) {
            const float* wp = wp1 + ((o0 + u) * 32 + ci) * 9;
            #pragma unroll
            for (int k = 0; k < 9; ++k)
                acc[u] = fmaf(wp[k], v[k], acc[u]);
        }
    }
    int hw = ((h0 + lh) << 7) + w0 + lw;
    float* op = p1 + (b << 19) + hw;
    #pragma unroll
    for (int u = 0; u < 16; ++u) op[(o0 + u) << 14] = prelu_(acc[u], ap);
}

// ---------------- K6: out = conv2(prelu(x2,a2))*attn + (wp2·p1+bp2) --------
// 8 splits x 16 out/thread x 4 px/thread (float4).
__global__ __launch_bounds__(256) void k_final(const float* __restrict__ x2,
        const float* __restrict__ p1, const float* __restrict__ attn,
        const float* __restrict__ a2p, const float* __restrict__ w2,
        const float* __restrict__ b2, const float* __restrict__ wp2,
        const float* __restrict__ bp2, float* __restrict__ out) {
    int tid = blockIdx.x * 256 + threadIdx.x;
    int pg = tid & (NPG - 1);
    int q = tid >> 13;               // 0..7, block-uniform
    int b = pg >> 12;
    int hw = (pg & 4095) << 2;
    int o0 = q * 16;
    const float a2 = a2p[0];
    float4 acc[16];
    #pragma unroll
    for (int u = 0; u < 16; ++u) { float bv = b2[o0 + u]; acc[u] = make_float4(bv, bv, bv, bv); }
    const float4* xp = (const float4*)(x2 + (b << 20) + hw);
    #pragma unroll 8
    for (int c = 0; c < 64; ++c) {
        float4 xv = xp[c << 12];
        xv.x = prelu_(xv.x, a2); xv.y = prelu_(xv.y, a2);
        xv.z = prelu_(xv.z, a2); xv.w = prelu_(xv.w, a2);
        #pragma unroll
        for (int u = 0; u < 16; ++u) {
            float wv = w2[(o0 + u) * 64 + c];
            acc[u].x = fmaf(wv, xv.x, acc[u].x);
            acc[u].y = fmaf(wv, xv.y, acc[u].y);
            acc[u].z = fmaf(wv, xv.z, acc[u].z);
            acc[u].w = fmaf(wv, xv.w, acc[u].w);
        }
    }
    float4 at = ((const float4*)attn)[pg];
    #pragma unroll
    for (int u = 0; u < 16; ++u) {
        float bv = bp2[o0 + u];
        acc[u].x = acc[u].x * at.x + bv;
        acc[u].y = acc[u].y * at.y + bv;
        acc[u].z = acc[u].z * at.z + bv;
        acc[u].w = acc[u].w * at.w + bv;
    }
    const float4* pp = (const float4*)(p1 + (b << 19) + hw);
    #pragma unroll 8
    for (int c = 0; c < 32; ++c) {
        float4 pv = pp[c << 12];
        #pragma unroll
        for (int u = 0; u < 16; ++u) {
            float wv = wp2[(o0 + u) * 32 + c];
            acc[u].x = fmaf(wv, pv.x, acc[u].x);
            acc[u].y = fmaf(wv, pv.y, acc[u].y);
            acc[u].z = fmaf(wv, pv.z, acc[u].z);
            acc[u].w = fmaf(wv, pv.w, acc[u].w);
        }
    }
    float4* op = (float4*)(out + ((b * 128 + o0) << 14) + hw);
    #pragma unroll
    for (int u = 0; u < 16; ++u) op[u << 12] = acc[u];
}

extern "C" void kernel_launch(void* const* d_in, const int* in_sizes, int n_in,
                              void* d_out, int out_size, void* d_ws, size_t ws_size,
                              hipStream_t stream) {
    const float* x   = (const float*)d_in[0];
    const float* w1  = (const float*)d_in[1];
    const float* b1  = (const float*)d_in[2];
    const float* a1  = (const float*)d_in[3];
    const float* wr  = (const float*)d_in[4];
    const float* br  = (const float*)d_in[5];
    const float* ws_ = (const float*)d_in[6];
    const float* bs  = (const float*)d_in[7];
    const float* a2  = (const float*)d_in[8];
    const float* w2  = (const float*)d_in[9];
    const float* b2  = (const float*)d_in[10];
    const float* wa  = (const float*)d_in[11];
    const float* ba  = (const float*)d_in[12];
    const float* wp1 = (const float*)d_in[13];
    const float* bp1 = (const float*)d_in[14];
    const float* ap  = (const float*)d_in[15];
    const float* wp2 = (const float*)d_in[16];
    const float* bp2 = (const float*)d_in[17];
    float* out = (float*)d_out;

    float* w = (float*)d_ws;
    float* ws_x1   = w;                        // 2*64*HW_
    float* ws_f    = ws_x1 + 2 * 64 * HW_;     // 2*32*HW_
    float* ws_x2   = ws_f  + 2 * 32 * HW_;     // 2*64*HW_
    float* ws_zp   = ws_x2 + 2 * 64 * HW_;     // 2*2*HW_
    float* ws_attn = ws_zp + 2 * 2 * HW_;      // NPX
    float* ws_p1   = ws_attn + NPX;            // 2*32*HW_

    hipLaunchKernelGGL(k_conv1, dim3(8 * NPG / 256), dim3(256), 0, stream,
                       x, w1, b1, a1, ws_x1);
    hipLaunchKernelGGL(k_reduce, dim3(4 * NPG / 128), dim3(128), 0, stream,
                       ws_x1, wr, br, ws_f);
    hipLaunchKernelGGL(k_invol, dim3(512), dim3(256), 0, stream,
                       ws_x1, ws_f, ws_, bs, ws_x2, ws_zp);
    hipLaunchKernelGGL(k_attn, dim3(NPX / 64), dim3(64), 0, stream,
                       ws_zp, wa, ba, ws_attn);
    hipLaunchKernelGGL(k_psec1, dim3(256), dim3(256), 0, stream,
                       ws_f, wp1, bp1, ap, ws_p1);
    hipLaunchKernelGGL(k_final, dim3(8 * NPG / 256), dim3(256), 0, stream,
                       ws_x2, ws_p1, ws_attn, a2, w2, b2, wp2, bp2, out);
}

// Round 5
// 263.715 us; speedup vs baseline: 1.3886x; 1.1476x over previous
//
#include <hip/hip_runtime.h>

#define HW_  16384   // H*W = 128*128
#define NPX  32768   // B*H*W
#define NPG  8192    // NPX/4 pixel-groups

__device__ __forceinline__ float prelu_(float x, float a) { return x >= 0.f ? x : a * x; }

// ---------------- K1: x1 = prelu(conv1x1(x, w1, b1), a1) ----------------
// 8 output-channel splits x 8 out/thread x 4 px/thread (float4 loads).
__global__ __launch_bounds__(256) void k_conv1(const float* __restrict__ x,
        const float* __restrict__ w1, const float* __restrict__ b1,
        const float* __restrict__ a1p, float* __restrict__ x1) {
    int tid = blockIdx.x * 256 + threadIdx.x;
    int pg = tid & (NPG - 1);
    int q = tid >> 13;               // 0..7, block-uniform
    int b = pg >> 12;
    int hw = (pg & 4095) << 2;
    int o0 = q * 8;
    const float a1 = a1p[0];
    float4 acc[8];
    #pragma unroll
    for (int u = 0; u < 8; ++u) { float bv = b1[o0 + u]; acc[u] = make_float4(bv, bv, bv, bv); }
    const float4* xp = (const float4*)(x + (b << 21) + hw);   // ch stride 4096 float4
    #pragma unroll 8
    for (int c = 0; c < 128; ++c) {
        float4 xv = xp[c << 12];
        #pragma unroll
        for (int u = 0; u < 8; ++u) {
            float wv = w1[(o0 + u) * 128 + c];
            acc[u].x = fmaf(wv, xv.x, acc[u].x);
            acc[u].y = fmaf(wv, xv.y, acc[u].y);
            acc[u].z = fmaf(wv, xv.z, acc[u].z);
            acc[u].w = fmaf(wv, xv.w, acc[u].w);
        }
    }
    float4* op = (float4*)(x1 + (b << 20) + hw);
    #pragma unroll
    for (int u = 0; u < 8; ++u) {
        float4 r;
        r.x = prelu_(acc[u].x, a1); r.y = prelu_(acc[u].y, a1);
        r.z = prelu_(acc[u].z, a1); r.w = prelu_(acc[u].w, a1);
        op[(o0 + u) << 12] = r;
    }
}

// ---------------- K2: f = relu(conv1x1(x1, wr, br)) ----------------
// 4 splits x 8 out/thread x 4 px/thread; 128-thread blocks for grid size.
__global__ __launch_bounds__(128) void k_reduce(const float* __restrict__ x1,
        const float* __restrict__ wr, const float* __restrict__ br,
        float* __restrict__ f) {
    int tid = blockIdx.x * 128 + threadIdx.x;
    int pg = tid & (NPG - 1);
    int q = tid >> 13;               // 0..3, block-uniform
    int b = pg >> 12;
    int hw = (pg & 4095) << 2;
    int o0 = q * 8;
    float4 acc[8];
    #pragma unroll
    for (int u = 0; u < 8; ++u) { float bv = br[o0 + u]; acc[u] = make_float4(bv, bv, bv, bv); }
    const float4* xp = (const float4*)(x1 + (b << 20) + hw);
    #pragma unroll 8
    for (int c = 0; c < 64; ++c) {
        float4 xv = xp[c << 12];
        #pragma unroll
        for (int u = 0; u < 8; ++u) {
            float wv = wr[(o0 + u) * 64 + c];
            acc[u].x = fmaf(wv, xv.x, acc[u].x);
            acc[u].y = fmaf(wv, xv.y, acc[u].y);
            acc[u].z = fmaf(wv, xv.z, acc[u].z);
            acc[u].w = fmaf(wv, xv.w, acc[u].w);
        }
    }
    float4* op = (float4*)(f + (b << 19) + hw);
    #pragma unroll
    for (int u = 0; u < 8; ++u) {
        float4 r;
        r.x = fmaxf(acc[u].x, 0.f); r.y = fmaxf(acc[u].y, 0.f);
        r.z = fmaxf(acc[u].z, 0.f); r.w = fmaxf(acc[u].w, 0.f);
        op[(o0 + u) << 12] = r;
    }
}

// ---------------- K3: fused span conv + involution -> x2 (+ ZPool on g==0) ----
// One block = one group g x one 16x16 pixel tile. x1 halo staged in LDS.
__global__ __launch_bounds__(256) void k_invol(const float* __restrict__ x1,
        const float* __restrict__ f, const float* __restrict__ ws_,
        const float* __restrict__ bs, float* __restrict__ x2,
        float* __restrict__ zp) {
    __shared__ float tile[16 * 22 * 24];   // [c][r][col], rowstride 24 (2-way alias = free)
    int g = blockIdx.x >> 7;               // 0..3, block-uniform
    int t = blockIdx.x & 127;              // b*64 + tile id
    int b = t >> 6;
    int th = (t >> 3) & 7, tw = t & 7;
    int h0 = th * 16, w0 = tw * 16;
    const float* x1g = x1 + ((b * 64 + g * 16) << 14);
    for (int e = threadIdx.x; e < 16 * 484; e += 256) {
        int c = e / 484;
        int rem = e - c * 484;
        int r = rem / 22, cl = rem - r * 22;
        int hh = h0 + r - 3, ww = w0 + cl - 3;
        float v = 0.f;
        if (hh >= 0 && hh < 128 && ww >= 0 && ww < 128)
            v = x1g[(c << 14) + (hh << 7) + ww];
        tile[c * 528 + r * 24 + cl] = v;
    }
    int lh = threadIdx.x >> 4, lw = threadIdx.x & 15;
    int hw = ((h0 + lh) << 7) + w0 + lw;
    float fv[32];
    const float* fp = f + (b << 19) + hw;
    #pragma unroll
    for (int c = 0; c < 32; ++c) fv[c] = fp[c << 14];
    if (g == 0) {                          // block-uniform: free ZPool
        float mx = fv[0], sm = fv[0];
        #pragma unroll
        for (int c = 1; c < 32; ++c) { mx = fmaxf(mx, fv[c]); sm += fv[c]; }
        zp[((b * 2 + 0) << 14) + hw] = mx;
        zp[((b * 2 + 1) << 14) + hw] = sm * (1.f / 32.f);
    }
    __syncthreads();
    float acc[16];
    #pragma unroll
    for (int u = 0; u < 16; ++u) acc[u] = 0.f;
    const float* tap0 = tile + lh * 24 + lw;
    const float* wk = ws_ + g * 49 * 32;
    const float* bsg = bs + g * 49;
    #pragma unroll 1
    for (int di = 0; di < 7; ++di) {
        #pragma unroll 1
        for (int dj = 0; dj < 7; ++dj) {
            int kk = di * 7 + dj;
            float kwv = bsg[kk];
            const float* wkk = wk + kk * 32;
            #pragma unroll
            for (int c = 0; c < 32; ++c) kwv = fmaf(wkk[c], fv[c], kwv);
            const float* tp = tap0 + di * 24 + dj;
            #pragma unroll
            for (int u = 0; u < 16; ++u)
                acc[u] = fmaf(kwv, tp[u * 528], acc[u]);
        }
    }
    float* op = x2 + ((b * 64 + g * 16) << 14) + hw;
    #pragma unroll
    for (int u = 0; u < 16; ++u) op[u << 14] = acc[u];
}

// ---------------- K4: attn = sigmoid(conv7x7(zp, wa, ba)) ----------------
__global__ __launch_bounds__(64) void k_attn(const float* __restrict__ zp,
        const float* __restrict__ wa, const float* __restrict__ ba,
        float* __restrict__ attn) {
    int px = blockIdx.x * 64 + threadIdx.x;
    int b = px >> 14, hw = px & (HW_ - 1);
    int h = hw >> 7, w = hw & 127;
    float acc = ba[0];
    for (int c = 0; c < 2; ++c)
        for (int i = 0; i < 7; ++i) {
            int hh = h + i - 3;
            if (hh < 0 || hh >= 128) continue;
            #pragma unroll
            for (int j = 0; j < 7; ++j) {
                int ww = w + j - 3;
                if (ww < 0 || ww >= 128) continue;
                acc = fmaf(wa[c * 49 + i * 7 + j],
                           zp[((b * 2 + c) << 14) + (hh << 7) + ww], acc);
            }
        }
    attn[px] = 1.f / (1.f + expf(-acc));
}

// ---------------- K5 v3: p1 = prelu(conv3x3(f, wp1, bp1), ap) ----------------
// Block = 16x16 px tile x 16 outs (2 splits). wp1 transposed into LDS (no SMEM
// in hot loop); f halo in LDS at row-stride 19 (odd -> taps spread over banks).
// Thread = 4 consecutive px x 4 outs.
__global__ __launch_bounds__(256) void k_psec1(const float* __restrict__ f,
        const float* __restrict__ wp1, const float* __restrict__ bp1,
        const float* __restrict__ app, float* __restrict__ p1) {
    __shared__ float fs[32 * 18 * 19];     // 43776 B: [ci][r(18)][cl(<=18)] stride 19
    __shared__ float wT[288 * 16];         // 18432 B: [(ci*9+k)][o-o0]
    int half = blockIdx.x >> 7;            // 0..1, block-uniform
    int t = blockIdx.x & 127;
    int b = t >> 6;
    int tile = t & 63;                     // 8x8 tiles of 16x16
    int th = tile >> 3, tw = tile & 7;
    int h0 = th * 16, w0 = tw * 16;
    int o0 = half * 16;

    // stage 16 outs' weights, transposed: wT[(ci*9+k)*16 + o] = wp1[(o0+o)*288 + ci*9+k]
    const float* wsrc = wp1 + o0 * 288;
    #pragma unroll 4
    for (int e = threadIdx.x; e < 4608; e += 256) {
        int o = e / 288, r = e - o * 288;
        wT[r * 16 + o] = wsrc[e];
    }
    // stage f halo: rows h0-1..h0+16, cols w0-1..w0+16
    const float* fb = f + (b << 19);
    #pragma unroll 4
    for (int e = threadIdx.x; e < 32 * 324; e += 256) {
        int ci = e / 324;
        int rem = e - ci * 324;
        int r = rem / 18, cl = rem - r * 18;
        int hh = h0 + r - 1, ww = w0 + cl - 1;
        float v = 0.f;
        if (hh >= 0 && hh < 128 && ww >= 0 && ww < 128)
            v = fb[(ci << 14) + (hh << 7) + ww];
        fs[ci * 342 + r * 19 + cl] = v;
    }
    __syncthreads();

    int pxq = threadIdx.x & 63;            // 64 px-quads cover the 256-px tile
    int rowq = pxq >> 2, colq = pxq & 3;   // row 0..15, col-quad 0..3
    int oh = threadIdx.x >> 6;             // 0..3 -> outs o0+oh*4 .. +3 (wave-uniform)
    const float ap = app[0];
    float acc[4][4];
    #pragma unroll
    for (int o = 0; o < 4; ++o) {
        float bv = bp1[o0 + oh * 4 + o];
        #pragma unroll
        for (int px = 0; px < 4; ++px) acc[o][px] = bv;
    }
    const float* fsb = fs + rowq * 19 + colq * 4;
    for (int ci = 0; ci < 32; ++ci) {
        float tap[3][6];
        const float* base = fsb + ci * 342;
        #pragma unroll
        for (int r = 0; r < 3; ++r)
            #pragma unroll
            for (int j = 0; j < 6; ++j)
                tap[r][j] = base[r * 19 + j];
        #pragma unroll
        for (int ki = 0; ki < 3; ++ki)
            #pragma unroll
            for (int kj = 0; kj < 3; ++kj) {
                const float* wv = &wT[((ci * 9 + ki * 3 + kj) << 4) + oh * 4];
                float w0v = wv[0], w1v = wv[1], w2v = wv[2], w3v = wv[3];
                #pragma unroll
                for (int px = 0; px < 4; ++px) {
                    float tv = tap[ki][px + kj];
                    acc[0][px] = fmaf(w0v, tv, acc[0][px]);
                    acc[1][px] = fmaf(w1v, tv, acc[1][px]);
                    acc[2][px] = fmaf(w2v, tv, acc[2][px]);
                    acc[3][px] = fmaf(w3v, tv, acc[3][px]);
                }
            }
    }
    int hw = ((h0 + rowq) << 7) + w0 + colq * 4;
    #pragma unroll
    for (int o = 0; o < 4; ++o) {
        float4 r;
        r.x = prelu_(acc[o][0], ap); r.y = prelu_(acc[o][1], ap);
        r.z = prelu_(acc[o][2], ap); r.w = prelu_(acc[o][3], ap);
        *(float4*)(p1 + ((b * 32 + o0 + oh * 4 + o) << 14) + hw) = r;
    }
}

// ---------------- K6: out = conv2(prelu(x2,a2))*attn + (wp2·p1+bp2) --------
// 8 splits x 16 out/thread x 4 px/thread (float4).
__global__ __launch_bounds__(256) void k_final(const float* __restrict__ x2,
        const float* __restrict__ p1, const float* __restrict__ attn,
        const float* __restrict__ a2p, const float* __restrict__ w2,
        const float* __restrict__ b2, const float* __restrict__ wp2,
        const float* __restrict__ bp2, float* __restrict__ out) {
    int tid = blockIdx.x * 256 + threadIdx.x;
    int pg = tid & (NPG - 1);
    int q = tid >> 13;               // 0..7, block-uniform
    int b = pg >> 12;
    int hw = (pg & 4095) << 2;
    int o0 = q * 16;
    const float a2 = a2p[0];
    float4 acc[16];
    #pragma unroll
    for (int u = 0; u < 16; ++u) { float bv = b2[o0 + u]; acc[u] = make_float4(bv, bv, bv, bv); }
    const float4* xp = (const float4*)(x2 + (b << 20) + hw);
    #pragma unroll 8
    for (int c = 0; c < 64; ++c) {
        float4 xv = xp[c << 12];
        xv.x = prelu_(xv.x, a2); xv.y = prelu_(xv.y, a2);
        xv.z = prelu_(xv.z, a2); xv.w = prelu_(xv.w, a2);
        #pragma unroll
        for (int u = 0; u < 16; ++u) {
            float wv = w2[(o0 + u) * 64 + c];
            acc[u].x = fmaf(wv, xv.x, acc[u].x);
            acc[u].y = fmaf(wv, xv.y, acc[u].y);
            acc[u].z = fmaf(wv, xv.z, acc[u].z);
            acc[u].w = fmaf(wv, xv.w, acc[u].w);
        }
    }
    float4 at = ((const float4*)attn)[pg];
    #pragma unroll
    for (int u = 0; u < 16; ++u) {
        float bv = bp2[o0 + u];
        acc[u].x = acc[u].x * at.x + bv;
        acc[u].y = acc[u].y * at.y + bv;
        acc[u].z = acc[u].z * at.z + bv;
        acc[u].w = acc[u].w * at.w + bv;
    }
    const float4* pp = (const float4*)(p1 + (b << 19) + hw);
    #pragma unroll 8
    for (int c = 0; c < 32; ++c) {
        float4 pv = pp[c << 12];
        #pragma unroll
        for (int u = 0; u < 16; ++u) {
            float wv = wp2[(o0 + u) * 32 + c];
            acc[u].x = fmaf(wv, pv.x, acc[u].x);
            acc[u].y = fmaf(wv, pv.y, acc[u].y);
            acc[u].z = fmaf(wv, pv.z, acc[u].z);
            acc[u].w = fmaf(wv, pv.w, acc[u].w);
        }
    }
    float4* op = (float4*)(out + ((b * 128 + o0) << 14) + hw);
    #pragma unroll
    for (int u = 0; u < 16; ++u) op[u << 12] = acc[u];
}

extern "C" void kernel_launch(void* const* d_in, const int* in_sizes, int n_in,
                              void* d_out, int out_size, void* d_ws, size_t ws_size,
                              hipStream_t stream) {
    const float* x   = (const float*)d_in[0];
    const float* w1  = (const float*)d_in[1];
    const float* b1  = (const float*)d_in[2];
    const float* a1  = (const float*)d_in[3];
    const float* wr  = (const float*)d_in[4];
    const float* br  = (const float*)d_in[5];
    const float* ws_ = (const float*)d_in[6];
    const float* bs  = (const float*)d_in[7];
    const float* a2  = (const float*)d_in[8];
    const float* w2  = (const float*)d_in[9];
    const float* b2  = (const float*)d_in[10];
    const float* wa  = (const float*)d_in[11];
    const float* ba  = (const float*)d_in[12];
    const float* wp1 = (const float*)d_in[13];
    const float* bp1 = (const float*)d_in[14];
    const float* ap  = (const float*)d_in[15];
    const float* wp2 = (const float*)d_in[16];
    const float* bp2 = (const float*)d_in[17];
    float* out = (float*)d_out;

    float* w = (float*)d_ws;
    float* ws_x1   = w;                        // 2*64*HW_
    float* ws_f    = ws_x1 + 2 * 64 * HW_;     // 2*32*HW_
    float* ws_x2   = ws_f  + 2 * 32 * HW_;     // 2*64*HW_
    float* ws_zp   = ws_x2 + 2 * 64 * HW_;     // 2*2*HW_
    float* ws_attn = ws_zp + 2 * 2 * HW_;      // NPX
    float* ws_p1   = ws_attn + NPX;            // 2*32*HW_

    hipLaunchKernelGGL(k_conv1, dim3(8 * NPG / 256), dim3(256), 0, stream,
                       x, w1, b1, a1, ws_x1);
    hipLaunchKernelGGL(k_reduce, dim3(4 * NPG / 128), dim3(128), 0, stream,
                       ws_x1, wr, br, ws_f);
    hipLaunchKernelGGL(k_invol, dim3(512), dim3(256), 0, stream,
                       ws_x1, ws_f, ws_, bs, ws_x2, ws_zp);
    hipLaunchKernelGGL(k_attn, dim3(NPX / 64), dim3(64), 0, stream,
                       ws_zp, wa, ba, ws_attn);
    hipLaunchKernelGGL(k_psec1, dim3(256), dim3(256), 0, stream,
                       ws_f, wp1, bp1, ap, ws_p1);
    hipLaunchKernelGGL(k_final, dim3(8 * NPG / 256), dim3(256), 0, stream,
                       ws_x2, ws_p1, ws_attn, a2, w2, b2, wp2, bp2, out);
}

// Round 6
// 228.047 us; speedup vs baseline: 1.6058x; 1.1564x over previous
//
#include <hip/hip_runtime.h>

#define HW_  16384   // H*W = 128*128
#define NPX  32768   // B*H*W
#define NPG  8192    // NPX/4 pixel-groups

__device__ __forceinline__ float prelu_(float x, float a) { return x >= 0.f ? x : a * x; }

// ---------------- K1: x1 = prelu(conv1x1(x, w1, b1), a1) ----------------
// 16 output-channel splits x 4 out/thread x 4 px/thread; explicit 8-deep load batches.
__global__ __launch_bounds__(256, 4) void k_conv1(const float* __restrict__ x,
        const float* __restrict__ w1, const float* __restrict__ b1,
        const float* __restrict__ a1p, float* __restrict__ x1) {
    int tid = blockIdx.x * 256 + threadIdx.x;
    int pg = tid & (NPG - 1);
    int q = tid >> 13;               // 0..15, block-uniform
    int b = pg >> 12;
    int hw = (pg & 4095) << 2;
    int o0 = q * 4;
    const float a1 = a1p[0];
    float4 acc[4];
    #pragma unroll
    for (int u = 0; u < 4; ++u) { float bv = b1[o0 + u]; acc[u] = make_float4(bv, bv, bv, bv); }
    const float4* xp = (const float4*)(x + (b << 21) + hw);   // ch stride 4096 float4
    #pragma unroll 1
    for (int cb = 0; cb < 16; ++cb) {
        float4 xv[8];
        #pragma unroll
        for (int j = 0; j < 8; ++j) xv[j] = xp[(cb * 8 + j) << 12];
        #pragma unroll
        for (int j = 0; j < 8; ++j) {
            int c = cb * 8 + j;
            #pragma unroll
            for (int u = 0; u < 4; ++u) {
                float wv = w1[(o0 + u) * 128 + c];
                acc[u].x = fmaf(wv, xv[j].x, acc[u].x);
                acc[u].y = fmaf(wv, xv[j].y, acc[u].y);
                acc[u].z = fmaf(wv, xv[j].z, acc[u].z);
                acc[u].w = fmaf(wv, xv[j].w, acc[u].w);
            }
        }
    }
    float4* op = (float4*)(x1 + (b << 20) + hw);
    #pragma unroll
    for (int u = 0; u < 4; ++u) {
        float4 r;
        r.x = prelu_(acc[u].x, a1); r.y = prelu_(acc[u].y, a1);
        r.z = prelu_(acc[u].z, a1); r.w = prelu_(acc[u].w, a1);
        op[(o0 + u) << 12] = r;
    }
}

// ---------------- K2: f = relu(conv1x1(x1, wr, br)) ----------------
// 8 splits x 4 out/thread x 2 px/thread (float2); 8-deep load batches.
__global__ __launch_bounds__(256, 4) void k_reduce(const float* __restrict__ x1,
        const float* __restrict__ wr, const float* __restrict__ br,
        float* __restrict__ f) {
    int tid = blockIdx.x * 256 + threadIdx.x;
    int p2 = tid & 16383;            // global px-pair 0..16383
    int q = tid >> 14;               // 0..7, block-uniform
    int b = p2 >> 13;
    int hw = (p2 & 8191) << 1;
    int o0 = q * 4;
    float2 acc[4];
    #pragma unroll
    for (int u = 0; u < 4; ++u) { float bv = br[o0 + u]; acc[u] = make_float2(bv, bv); }
    const float2* xp = (const float2*)(x1 + (b << 20) + hw);  // ch stride 8192 float2
    #pragma unroll 1
    for (int cb = 0; cb < 8; ++cb) {
        float2 xv[8];
        #pragma unroll
        for (int j = 0; j < 8; ++j) xv[j] = xp[(cb * 8 + j) << 13];
        #pragma unroll
        for (int j = 0; j < 8; ++j) {
            int c = cb * 8 + j;
            #pragma unroll
            for (int u = 0; u < 4; ++u) {
                float wv = wr[(o0 + u) * 64 + c];
                acc[u].x = fmaf(wv, xv[j].x, acc[u].x);
                acc[u].y = fmaf(wv, xv[j].y, acc[u].y);
            }
        }
    }
    float2* op = (float2*)(f + (b << 19) + hw);
    #pragma unroll
    for (int u = 0; u < 4; ++u) {
        float2 r;
        r.x = fmaxf(acc[u].x, 0.f); r.y = fmaxf(acc[u].y, 0.f);
        op[(o0 + u) << 13] = r;
    }
}

// ---------------- K3: fused span conv + involution -> x2 (+ ZPool on g==0) ----
// One block = one group g x one 16x16 pixel tile. x1 halo staged in LDS.
__global__ __launch_bounds__(256) void k_invol(const float* __restrict__ x1,
        const float* __restrict__ f, const float* __restrict__ ws_,
        const float* __restrict__ bs, float* __restrict__ x2,
        float* __restrict__ zp) {
    __shared__ float tile[16 * 22 * 24];   // [c][r][col], rowstride 24 (2-way alias = free)
    int g = blockIdx.x >> 7;               // 0..3, block-uniform
    int t = blockIdx.x & 127;              // b*64 + tile id
    int b = t >> 6;
    int th = (t >> 3) & 7, tw = t & 7;
    int h0 = th * 16, w0 = tw * 16;
    const float* x1g = x1 + ((b * 64 + g * 16) << 14);
    for (int e = threadIdx.x; e < 16 * 484; e += 256) {
        int c = e / 484;
        int rem = e - c * 484;
        int r = rem / 22, cl = rem - r * 22;
        int hh = h0 + r - 3, ww = w0 + cl - 3;
        float v = 0.f;
        if (hh >= 0 && hh < 128 && ww >= 0 && ww < 128)
            v = x1g[(c << 14) + (hh << 7) + ww];
        tile[c * 528 + r * 24 + cl] = v;
    }
    int lh = threadIdx.x >> 4, lw = threadIdx.x & 15;
    int hw = ((h0 + lh) << 7) + w0 + lw;
    float fv[32];
    const float* fp = f + (b << 19) + hw;
    #pragma unroll
    for (int c = 0; c < 32; ++c) fv[c] = fp[c << 14];
    if (g == 0) {                          // block-uniform: free ZPool
        float mx = fv[0], sm = fv[0];
        #pragma unroll
        for (int c = 1; c < 32; ++c) { mx = fmaxf(mx, fv[c]); sm += fv[c]; }
        zp[((b * 2 + 0) << 14) + hw] = mx;
        zp[((b * 2 + 1) << 14) + hw] = sm * (1.f / 32.f);
    }
    __syncthreads();
    float acc[16];
    #pragma unroll
    for (int u = 0; u < 16; ++u) acc[u] = 0.f;
    const float* tap0 = tile + lh * 24 + lw;
    const float* wk = ws_ + g * 49 * 32;
    const float* bsg = bs + g * 49;
    #pragma unroll 1
    for (int di = 0; di < 7; ++di) {
        #pragma unroll 1
        for (int dj = 0; dj < 7; ++dj) {
            int kk = di * 7 + dj;
            float kwv = bsg[kk];
            const float* wkk = wk + kk * 32;
            #pragma unroll
            for (int c = 0; c < 32; ++c) kwv = fmaf(wkk[c], fv[c], kwv);
            const float* tp = tap0 + di * 24 + dj;
            #pragma unroll
            for (int u = 0; u < 16; ++u)
                acc[u] = fmaf(kwv, tp[u * 528], acc[u]);
        }
    }
    float* op = x2 + ((b * 64 + g * 16) << 14) + hw;
    #pragma unroll
    for (int u = 0; u < 16; ++u) op[u << 14] = acc[u];
}

// ---------------- K4: attn = sigmoid(conv7x7(zp, wa, ba)) ----------------
__global__ __launch_bounds__(64) void k_attn(const float* __restrict__ zp,
        const float* __restrict__ wa, const float* __restrict__ ba,
        float* __restrict__ attn) {
    int px = blockIdx.x * 64 + threadIdx.x;
    int b = px >> 14, hw = px & (HW_ - 1);
    int h = hw >> 7, w = hw & 127;
    float acc = ba[0];
    for (int c = 0; c < 2; ++c)
        for (int i = 0; i < 7; ++i) {
            int hh = h + i - 3;
            if (hh < 0 || hh >= 128) continue;
            #pragma unroll
            for (int j = 0; j < 7; ++j) {
                int ww = w + j - 3;
                if (ww < 0 || ww >= 128) continue;
                acc = fmaf(wa[c * 49 + i * 7 + j],
                           zp[((b * 2 + c) << 14) + (hh << 7) + ww], acc);
            }
        }
    attn[px] = 1.f / (1.f + expf(-acc));
}

// ---------------- K5: p1 = prelu(conv3x3(f, wp1, bp1), ap) ----------------
// Block = 16x16 px tile x 16 outs (2 splits). wp1 transposed into LDS; f halo
// in LDS at row-stride 19. Thread = 4 consecutive px x 4 outs.
__global__ __launch_bounds__(256) void k_psec1(const float* __restrict__ f,
        const float* __restrict__ wp1, const float* __restrict__ bp1,
        const float* __restrict__ app, float* __restrict__ p1) {
    __shared__ float fs[32 * 18 * 19];     // 43776 B
    __shared__ float wT[288 * 16];         // 18432 B
    int half = blockIdx.x >> 7;            // 0..1, block-uniform
    int t = blockIdx.x & 127;
    int b = t >> 6;
    int tile = t & 63;
    int th = tile >> 3, tw = tile & 7;
    int h0 = th * 16, w0 = tw * 16;
    int o0 = half * 16;

    const float* wsrc = wp1 + o0 * 288;
    #pragma unroll 4
    for (int e = threadIdx.x; e < 4608; e += 256) {
        int o = e / 288, r = e - o * 288;
        wT[r * 16 + o] = wsrc[e];
    }
    const float* fb = f + (b << 19);
    #pragma unroll 4
    for (int e = threadIdx.x; e < 32 * 324; e += 256) {
        int ci = e / 324;
        int rem = e - ci * 324;
        int r = rem / 18, cl = rem - r * 18;
        int hh = h0 + r - 1, ww = w0 + cl - 1;
        float v = 0.f;
        if (hh >= 0 && hh < 128 && ww >= 0 && ww < 128)
            v = fb[(ci << 14) + (hh << 7) + ww];
        fs[ci * 342 + r * 19 + cl] = v;
    }
    __syncthreads();

    int pxq = threadIdx.x & 63;
    int rowq = pxq >> 2, colq = pxq & 3;
    int oh = threadIdx.x >> 6;             // 0..3, wave-uniform
    const float ap = app[0];
    float acc[4][4];
    #pragma unroll
    for (int o = 0; o < 4; ++o) {
        float bv = bp1[o0 + oh * 4 + o];
        #pragma unroll
        for (int px = 0; px < 4; ++px) acc[o][px] = bv;
    }
    const float* fsb = fs + rowq * 19 + colq * 4;
    for (int ci = 0; ci < 32; ++ci) {
        float tap[3][6];
        const float* base = fsb + ci * 342;
        #pragma unroll
        for (int r = 0; r < 3; ++r)
            #pragma unroll
            for (int j = 0; j < 6; ++j)
                tap[r][j] = base[r * 19 + j];
        #pragma unroll
        for (int ki = 0; ki < 3; ++ki)
            #pragma unroll
            for (int kj = 0; kj < 3; ++kj) {
                const float* wv = &wT[((ci * 9 + ki * 3 + kj) << 4) + oh * 4];
                float w0v = wv[0], w1v = wv[1], w2v = wv[2], w3v = wv[3];
                #pragma unroll
                for (int px = 0; px < 4; ++px) {
                    float tv = tap[ki][px + kj];
                    acc[0][px] = fmaf(w0v, tv, acc[0][px]);
                    acc[1][px] = fmaf(w1v, tv, acc[1][px]);
                    acc[2][px] = fmaf(w2v, tv, acc[2][px]);
                    acc[3][px] = fmaf(w3v, tv, acc[3][px]);
                }
            }
    }
    int hw = ((h0 + rowq) << 7) + w0 + colq * 4;
    #pragma unroll
    for (int o = 0; o < 4; ++o) {
        float4 r;
        r.x = prelu_(acc[o][0], ap); r.y = prelu_(acc[o][1], ap);
        r.z = prelu_(acc[o][2], ap); r.w = prelu_(acc[o][3], ap);
        *(float4*)(p1 + ((b * 32 + o0 + oh * 4 + o) << 14) + hw) = r;
    }
}

// ---------------- K6: out = conv2(prelu(x2,a2))*attn + (wp2·p1+bp2) --------
// 32 splits x 4 out/thread x 4 px/thread; 8-deep load batches.
__global__ __launch_bounds__(256, 4) void k_final(const float* __restrict__ x2,
        const float* __restrict__ p1, const float* __restrict__ attn,
        const float* __restrict__ a2p, const float* __restrict__ w2,
        const float* __restrict__ b2, const float* __restrict__ wp2,
        const float* __restrict__ bp2, float* __restrict__ out) {
    int tid = blockIdx.x * 256 + threadIdx.x;
    int pg = tid & (NPG - 1);
    int q = tid >> 13;               // 0..31, block-uniform
    int b = pg >> 12;
    int hw = (pg & 4095) << 2;
    int o0 = q * 4;
    const float a2 = a2p[0];
    float4 acc[4];
    #pragma unroll
    for (int u = 0; u < 4; ++u) { float bv = b2[o0 + u]; acc[u] = make_float4(bv, bv, bv, bv); }
    const float4* xp = (const float4*)(x2 + (b << 20) + hw);
    #pragma unroll 1
    for (int cb = 0; cb < 8; ++cb) {
        float4 xv[8];
        #pragma unroll
        for (int j = 0; j < 8; ++j) xv[j] = xp[(cb * 8 + j) << 12];
        #pragma unroll
        for (int j = 0; j < 8; ++j) {
            float4 v = xv[j];
            v.x = prelu_(v.x, a2); v.y = prelu_(v.y, a2);
            v.z = prelu_(v.z, a2); v.w = prelu_(v.w, a2);
            int c = cb * 8 + j;
            #pragma unroll
            for (int u = 0; u < 4; ++u) {
                float wv = w2[(o0 + u) * 64 + c];
                acc[u].x = fmaf(wv, v.x, acc[u].x);
                acc[u].y = fmaf(wv, v.y, acc[u].y);
                acc[u].z = fmaf(wv, v.z, acc[u].z);
                acc[u].w = fmaf(wv, v.w, acc[u].w);
            }
        }
    }
    float4 at = ((const float4*)attn)[pg];
    #pragma unroll
    for (int u = 0; u < 4; ++u) {
        float bv = bp2[o0 + u];
        acc[u].x = acc[u].x * at.x + bv;
        acc[u].y = acc[u].y * at.y + bv;
        acc[u].z = acc[u].z * at.z + bv;
        acc[u].w = acc[u].w * at.w + bv;
    }
    const float4* pp = (const float4*)(p1 + (b << 19) + hw);
    #pragma unroll 1
    for (int cb = 0; cb < 4; ++cb) {
        float4 pv[8];
        #pragma unroll
        for (int j = 0; j < 8; ++j) pv[j] = pp[(cb * 8 + j) << 12];
        #pragma unroll
        for (int j = 0; j < 8; ++j) {
            int c = cb * 8 + j;
            #pragma unroll
            for (int u = 0; u < 4; ++u) {
                float wv = wp2[(o0 + u) * 32 + c];
                acc[u].x = fmaf(wv, pv[j].x, acc[u].x);
                acc[u].y = fmaf(wv, pv[j].y, acc[u].y);
                acc[u].z = fmaf(wv, pv[j].z, acc[u].z);
                acc[u].w = fmaf(wv, pv[j].w, acc[u].w);
            }
        }
    }
    float4* op = (float4*)(out + ((b * 128 + o0) << 14) + hw);
    #pragma unroll
    for (int u = 0; u < 4; ++u) op[u << 12] = acc[u];
}

extern "C" void kernel_launch(void* const* d_in, const int* in_sizes, int n_in,
                              void* d_out, int out_size, void* d_ws, size_t ws_size,
                              hipStream_t stream) {
    const float* x   = (const float*)d_in[0];
    const float* w1  = (const float*)d_in[1];
    const float* b1  = (const float*)d_in[2];
    const float* a1  = (const float*)d_in[3];
    const float* wr  = (const float*)d_in[4];
    const float* br  = (const float*)d_in[5];
    const float* ws_ = (const float*)d_in[6];
    const float* bs  = (const float*)d_in[7];
    const float* a2  = (const float*)d_in[8];
    const float* w2  = (const float*)d_in[9];
    const float* b2  = (const float*)d_in[10];
    const float* wa  = (const float*)d_in[11];
    const float* ba  = (const float*)d_in[12];
    const float* wp1 = (const float*)d_in[13];
    const float* bp1 = (const float*)d_in[14];
    const float* ap  = (const float*)d_in[15];
    const float* wp2 = (const float*)d_in[16];
    const float* bp2 = (const float*)d_in[17];
    float* out = (float*)d_out;

    float* w = (float*)d_ws;
    float* ws_x1   = w;                        // 2*64*HW_
    float* ws_f    = ws_x1 + 2 * 64 * HW_;     // 2*32*HW_
    float* ws_x2   = ws_f  + 2 * 32 * HW_;     // 2*64*HW_
    float* ws_zp   = ws_x2 + 2 * 64 * HW_;     // 2*2*HW_
    float* ws_attn = ws_zp + 2 * 2 * HW_;      // NPX
    float* ws_p1   = ws_attn + NPX;            // 2*32*HW_

    hipLaunchKernelGGL(k_conv1, dim3(16 * NPG / 256), dim3(256), 0, stream,
                       x, w1, b1, a1, ws_x1);
    hipLaunchKernelGGL(k_reduce, dim3(8 * 16384 / 256), dim3(256), 0, stream,
                       ws_x1, wr, br, ws_f);
    hipLaunchKernelGGL(k_invol, dim3(512), dim3(256), 0, stream,
                       ws_x1, ws_f, ws_, bs, ws_x2, ws_zp);
    hipLaunchKernelGGL(k_attn, dim3(NPX / 64), dim3(64), 0, stream,
                       ws_zp, wa, ba, ws_attn);
    hipLaunchKernelGGL(k_psec1, dim3(256), dim3(256), 0, stream,
                       ws_f, wp1, bp1, ap, ws_p1);
    hipLaunchKernelGGL(k_final, dim3(32 * NPG / 256), dim3(256), 0, stream,
                       ws_x2, ws_p1, ws_attn, a2, w2, b2, wp2, bp2, out);
}

// Round 7
// 209.583 us; speedup vs baseline: 1.7473x; 1.0881x over previous
//
#include <hip/hip_runtime.h>

#define HW_  16384   // H*W = 128*128
#define NPX  32768   // B*H*W
#define NPG  8192    // NPX/4 pixel-groups

__device__ __forceinline__ float prelu_(float x, float a) { return x >= 0.f ? x : a * x; }

// ---------------- K1: x1 = prelu(conv1x1(x, w1, b1), a1) ----------------
// 16 output-channel splits x 4 out/thread x 4 px/thread; 16-deep load batches.
__global__ __launch_bounds__(256, 4) void k_conv1(const float* __restrict__ x,
        const float* __restrict__ w1, const float* __restrict__ b1,
        const float* __restrict__ a1p, float* __restrict__ x1) {
    int tid = blockIdx.x * 256 + threadIdx.x;
    int pg = tid & (NPG - 1);
    int q = tid >> 13;               // 0..15, block-uniform
    int b = pg >> 12;
    int hw = (pg & 4095) << 2;
    int o0 = q * 4;
    const float a1 = a1p[0];
    float4 acc[4];
    #pragma unroll
    for (int u = 0; u < 4; ++u) { float bv = b1[o0 + u]; acc[u] = make_float4(bv, bv, bv, bv); }
    const float4* xp = (const float4*)(x + (b << 21) + hw);   // ch stride 4096 float4
    #pragma unroll 1
    for (int cb = 0; cb < 8; ++cb) {
        float4 xv[16];
        #pragma unroll
        for (int j = 0; j < 16; ++j) xv[j] = xp[(cb * 16 + j) << 12];
        #pragma unroll
        for (int j = 0; j < 16; ++j) {
            int c = cb * 16 + j;
            #pragma unroll
            for (int u = 0; u < 4; ++u) {
                float wv = w1[(o0 + u) * 128 + c];
                acc[u].x = fmaf(wv, xv[j].x, acc[u].x);
                acc[u].y = fmaf(wv, xv[j].y, acc[u].y);
                acc[u].z = fmaf(wv, xv[j].z, acc[u].z);
                acc[u].w = fmaf(wv, xv[j].w, acc[u].w);
            }
        }
    }
    float4* op = (float4*)(x1 + (b << 20) + hw);
    #pragma unroll
    for (int u = 0; u < 4; ++u) {
        float4 r;
        r.x = prelu_(acc[u].x, a1); r.y = prelu_(acc[u].y, a1);
        r.z = prelu_(acc[u].z, a1); r.w = prelu_(acc[u].w, a1);
        op[(o0 + u) << 12] = r;
    }
}

// ---------------- K2: f = relu(conv1x1(x1, wr, br)) ----------------
// 8 splits x 4 out/thread x 2 px/thread (float2); 16-deep load batches.
__global__ __launch_bounds__(256, 4) void k_reduce(const float* __restrict__ x1,
        const float* __restrict__ wr, const float* __restrict__ br,
        float* __restrict__ f) {
    int tid = blockIdx.x * 256 + threadIdx.x;
    int p2 = tid & 16383;            // global px-pair 0..16383
    int q = tid >> 14;               // 0..7, block-uniform
    int b = p2 >> 13;
    int hw = (p2 & 8191) << 1;
    int o0 = q * 4;
    float2 acc[4];
    #pragma unroll
    for (int u = 0; u < 4; ++u) { float bv = br[o0 + u]; acc[u] = make_float2(bv, bv); }
    const float2* xp = (const float2*)(x1 + (b << 20) + hw);  // ch stride 8192 float2
    #pragma unroll 1
    for (int cb = 0; cb < 4; ++cb) {
        float2 xv[16];
        #pragma unroll
        for (int j = 0; j < 16; ++j) xv[j] = xp[(cb * 16 + j) << 13];
        #pragma unroll
        for (int j = 0; j < 16; ++j) {
            int c = cb * 16 + j;
            #pragma unroll
            for (int u = 0; u < 4; ++u) {
                float wv = wr[(o0 + u) * 64 + c];
                acc[u].x = fmaf(wv, xv[j].x, acc[u].x);
                acc[u].y = fmaf(wv, xv[j].y, acc[u].y);
            }
        }
    }
    float2* op = (float2*)(f + (b << 19) + hw);
    #pragma unroll
    for (int u = 0; u < 4; ++u) {
        float2 r;
        r.x = fmaxf(acc[u].x, 0.f); r.y = fmaxf(acc[u].y, 0.f);
        op[(o0 + u) << 13] = r;
    }
}

// ---------------- K3: fused span conv + involution -> x2 (+ ZPool on g==0) ----
// One block = one group g x one 16x16 pixel tile. x1 halo staged in LDS;
// staging: guard once per halo pixel, 16 channel loads clustered.
__global__ __launch_bounds__(256) void k_invol(const float* __restrict__ x1,
        const float* __restrict__ f, const float* __restrict__ ws_,
        const float* __restrict__ bs, float* __restrict__ x2,
        float* __restrict__ zp) {
    __shared__ float tile[16 * 22 * 24];   // [c][r][col], rowstride 24 (2-way alias = free)
    int g = blockIdx.x >> 7;               // 0..3, block-uniform
    int t = blockIdx.x & 127;              // b*64 + tile id
    int b = t >> 6;
    int th = (t >> 3) & 7, tw = t & 7;
    int h0 = th * 16, w0 = tw * 16;
    const float* x1g = x1 + ((b * 64 + g * 16) << 14);
    #pragma unroll 1
    for (int rem = threadIdx.x; rem < 484; rem += 256) {
        int r = rem / 22, cl = rem - r * 22;
        int hh = h0 + r - 3, ww = w0 + cl - 3;
        bool ok = (hh >= 0 && hh < 128 && ww >= 0 && ww < 128);
        const float* src = x1g + (hh << 7) + ww;
        float v[16];
        #pragma unroll
        for (int c = 0; c < 16; ++c) v[c] = ok ? src[c << 14] : 0.f;
        float* dst = tile + r * 24 + cl;
        #pragma unroll
        for (int c = 0; c < 16; ++c) dst[c * 528] = v[c];
    }
    int lh = threadIdx.x >> 4, lw = threadIdx.x & 15;
    int hw = ((h0 + lh) << 7) + w0 + lw;
    float fv[32];
    const float* fp = f + (b << 19) + hw;
    #pragma unroll
    for (int c = 0; c < 32; ++c) fv[c] = fp[c << 14];
    if (g == 0) {                          // block-uniform: free ZPool
        float mx = fv[0], sm = fv[0];
        #pragma unroll
        for (int c = 1; c < 32; ++c) { mx = fmaxf(mx, fv[c]); sm += fv[c]; }
        zp[((b * 2 + 0) << 14) + hw] = mx;
        zp[((b * 2 + 1) << 14) + hw] = sm * (1.f / 32.f);
    }
    __syncthreads();
    float acc[16];
    #pragma unroll
    for (int u = 0; u < 16; ++u) acc[u] = 0.f;
    const float* tap0 = tile + lh * 24 + lw;
    const float* wk = ws_ + g * 49 * 32;
    const float* bsg = bs + g * 49;
    #pragma unroll 1
    for (int di = 0; di < 7; ++di) {
        #pragma unroll 1
        for (int dj = 0; dj < 7; ++dj) {
            int kk = di * 7 + dj;
            float kwv = bsg[kk];
            const float* wkk = wk + kk * 32;
            #pragma unroll
            for (int c = 0; c < 32; ++c) kwv = fmaf(wkk[c], fv[c], kwv);
            const float* tp = tap0 + di * 24 + dj;
            #pragma unroll
            for (int u = 0; u < 16; ++u)
                acc[u] = fmaf(kwv, tp[u * 528], acc[u]);
        }
    }
    float* op = x2 + ((b * 64 + g * 16) << 14) + hw;
    #pragma unroll
    for (int u = 0; u < 16; ++u) op[u << 14] = acc[u];
}

// ---------------- K4: attn = sigmoid(conv7x7(zp, wa, ba)) ----------------
// One block = one 16x16 tile; zp halo (2 x 22x22) in LDS.
__global__ __launch_bounds__(256) void k_attn(const float* __restrict__ zp,
        const float* __restrict__ wa, const float* __restrict__ ba,
        float* __restrict__ attn) {
    __shared__ float zs[2][22 * 23];       // stride 23
    int t = blockIdx.x;                    // 0..127
    int b = t >> 6;
    int tile = t & 63;
    int th = tile >> 3, tw = tile & 7;
    int h0 = th * 16, w0 = tw * 16;
    const float* zb = zp + (b << 15);      // b*2*HW_
    #pragma unroll 1
    for (int rem = threadIdx.x; rem < 484; rem += 256) {
        int r = rem / 22, cl = rem - r * 22;
        int hh = h0 + r - 3, ww = w0 + cl - 3;
        bool ok = (hh >= 0 && hh < 128 && ww >= 0 && ww < 128);
        const float* src = zb + (hh << 7) + ww;
        float v0 = ok ? src[0] : 0.f;
        float v1 = ok ? src[HW_] : 0.f;
        zs[0][r * 23 + cl] = v0;
        zs[1][r * 23 + cl] = v1;
    }
    __syncthreads();
    int lh = threadIdx.x >> 4, lw = threadIdx.x & 15;
    float acc = ba[0];
    #pragma unroll
    for (int c = 0; c < 2; ++c) {
        const float* zc = &zs[c][lh * 23 + lw];
        #pragma unroll
        for (int i = 0; i < 7; ++i)
            #pragma unroll
            for (int j = 0; j < 7; ++j)
                acc = fmaf(wa[c * 49 + i * 7 + j], zc[i * 23 + j], acc);
    }
    attn[(b << 14) + ((h0 + lh) << 7) + w0 + lw] = 1.f / (1.f + expf(-acc));
}

// ---------------- K5: p1 = prelu(conv3x3(f, wp1, bp1), ap) ----------------
// Block = 16x16 px tile x 16 outs (2 splits). wp1 transposed into LDS; f halo
// in LDS at row-stride 19. Staging: guard once per halo pixel, 8-deep clusters.
__global__ __launch_bounds__(256) void k_psec1(const float* __restrict__ f,
        const float* __restrict__ wp1, const float* __restrict__ bp1,
        const float* __restrict__ app, float* __restrict__ p1) {
    __shared__ float fs[32 * 18 * 19];     // 43776 B
    __shared__ float wT[288 * 16];         // 18432 B
    int half = blockIdx.x >> 7;            // 0..1, block-uniform
    int t = blockIdx.x & 127;
    int b = t >> 6;
    int tile = t & 63;
    int th = tile >> 3, tw = tile & 7;
    int h0 = th * 16, w0 = tw * 16;
    int o0 = half * 16;

    // weights: float4 global loads, transposed scatter into LDS
    const float4* wsrc4 = (const float4*)(wp1 + o0 * 288);   // 72 float4 per o
    #pragma unroll 1
    for (int e4 = threadIdx.x; e4 < 1152; e4 += 256) {
        float4 v = wsrc4[e4];
        int o = e4 / 72, r4 = (e4 - o * 72) * 4;
        wT[(r4 + 0) * 16 + o] = v.x;
        wT[(r4 + 1) * 16 + o] = v.y;
        wT[(r4 + 2) * 16 + o] = v.z;
        wT[(r4 + 3) * 16 + o] = v.w;
    }
    // f halo: guard once per pixel, 8-deep channel clusters
    const float* fb = f + (b << 19);
    #pragma unroll 1
    for (int rem = threadIdx.x; rem < 324; rem += 256) {
        int r = rem / 18, cl = rem - r * 18;
        int hh = h0 + r - 1, ww = w0 + cl - 1;
        bool ok = (hh >= 0 && hh < 128 && ww >= 0 && ww < 128);
        const float* src = fb + (hh << 7) + ww;
        float* dst = fs + r * 19 + cl;
        #pragma unroll 1
        for (int cb = 0; cb < 4; ++cb) {
            float v[8];
            #pragma unroll
            for (int c = 0; c < 8; ++c) v[c] = ok ? src[(cb * 8 + c) << 14] : 0.f;
            #pragma unroll
            for (int c = 0; c < 8; ++c) dst[(cb * 8 + c) * 342] = v[c];
        }
    }
    __syncthreads();

    int pxq = threadIdx.x & 63;
    int rowq = pxq >> 2, colq = pxq & 3;
    int oh = threadIdx.x >> 6;             // 0..3, wave-uniform
    const float ap = app[0];
    float acc[4][4];
    #pragma unroll
    for (int o = 0; o < 4; ++o) {
        float bv = bp1[o0 + oh * 4 + o];
        #pragma unroll
        for (int px = 0; px < 4; ++px) acc[o][px] = bv;
    }
    const float* fsb = fs + rowq * 19 + colq * 4;
    for (int ci = 0; ci < 32; ++ci) {
        float tap[3][6];
        const float* base = fsb + ci * 342;
        #pragma unroll
        for (int r = 0; r < 3; ++r)
            #pragma unroll
            for (int j = 0; j < 6; ++j)
                tap[r][j] = base[r * 19 + j];
        #pragma unroll
        for (int ki = 0; ki < 3; ++ki)
            #pragma unroll
            for (int kj = 0; kj < 3; ++kj) {
                const float* wv = &wT[((ci * 9 + ki * 3 + kj) << 4) + oh * 4];
                float w0v = wv[0], w1v = wv[1], w2v = wv[2], w3v = wv[3];
                #pragma unroll
                for (int px = 0; px < 4; ++px) {
                    float tv = tap[ki][px + kj];
                    acc[0][px] = fmaf(w0v, tv, acc[0][px]);
                    acc[1][px] = fmaf(w1v, tv, acc[1][px]);
                    acc[2][px] = fmaf(w2v, tv, acc[2][px]);
                    acc[3][px] = fmaf(w3v, tv, acc[3][px]);
                }
            }
    }
    int hw = ((h0 + rowq) << 7) + w0 + colq * 4;
    #pragma unroll
    for (int o = 0; o < 4; ++o) {
        float4 r;
        r.x = prelu_(acc[o][0], ap); r.y = prelu_(acc[o][1], ap);
        r.z = prelu_(acc[o][2], ap); r.w = prelu_(acc[o][3], ap);
        *(float4*)(p1 + ((b * 32 + o0 + oh * 4 + o) << 14) + hw) = r;
    }
}

// ---------------- K6: out = conv2(prelu(x2,a2))*attn + (wp2·p1+bp2) --------
// 32 splits x 4 out/thread x 4 px/thread; 16-deep load batches.
__global__ __launch_bounds__(256, 4) void k_final(const float* __restrict__ x2,
        const float* __restrict__ p1, const float* __restrict__ attn,
        const float* __restrict__ a2p, const float* __restrict__ w2,
        const float* __restrict__ b2, const float* __restrict__ wp2,
        const float* __restrict__ bp2, float* __restrict__ out) {
    int tid = blockIdx.x * 256 + threadIdx.x;
    int pg = tid & (NPG - 1);
    int q = tid >> 13;               // 0..31, block-uniform
    int b = pg >> 12;
    int hw = (pg & 4095) << 2;
    int o0 = q * 4;
    const float a2 = a2p[0];
    float4 acc[4];
    #pragma unroll
    for (int u = 0; u < 4; ++u) { float bv = b2[o0 + u]; acc[u] = make_float4(bv, bv, bv, bv); }
    const float4* xp = (const float4*)(x2 + (b << 20) + hw);
    #pragma unroll 1
    for (int cb = 0; cb < 4; ++cb) {
        float4 xv[16];
        #pragma unroll
        for (int j = 0; j < 16; ++j) xv[j] = xp[(cb * 16 + j) << 12];
        #pragma unroll
        for (int j = 0; j < 16; ++j) {
            float4 v = xv[j];
            v.x = prelu_(v.x, a2); v.y = prelu_(v.y, a2);
            v.z = prelu_(v.z, a2); v.w = prelu_(v.w, a2);
            int c = cb * 16 + j;
            #pragma unroll
            for (int u = 0; u < 4; ++u) {
                float wv = w2[(o0 + u) * 64 + c];
                acc[u].x = fmaf(wv, v.x, acc[u].x);
                acc[u].y = fmaf(wv, v.y, acc[u].y);
                acc[u].z = fmaf(wv, v.z, acc[u].z);
                acc[u].w = fmaf(wv, v.w, acc[u].w);
            }
        }
    }
    float4 at = ((const float4*)attn)[pg];
    #pragma unroll
    for (int u = 0; u < 4; ++u) {
        float bv = bp2[o0 + u];
        acc[u].x = acc[u].x * at.x + bv;
        acc[u].y = acc[u].y * at.y + bv;
        acc[u].z = acc[u].z * at.z + bv;
        acc[u].w = acc[u].w * at.w + bv;
    }
    const float4* pp = (const float4*)(p1 + (b << 19) + hw);
    #pragma unroll 1
    for (int cb = 0; cb < 2; ++cb) {
        float4 pv[16];
        #pragma unroll
        for (int j = 0; j < 16; ++j) pv[j] = pp[(cb * 16 + j) << 12];
        #pragma unroll
        for (int j = 0; j < 16; ++j) {
            int c = cb * 16 + j;
            #pragma unroll
            for (int u = 0; u < 4; ++u) {
                float wv = wp2[(o0 + u) * 32 + c];
                acc[u].x = fmaf(wv, pv[j].x, acc[u].x);
                acc[u].y = fmaf(wv, pv[j].y, acc[u].y);
                acc[u].z = fmaf(wv, pv[j].z, acc[u].z);
                acc[u].w = fmaf(wv, pv[j].w, acc[u].w);
            }
        }
    }
    float4* op = (float4*)(out + ((b * 128 + o0) << 14) + hw);
    #pragma unroll
    for (int u = 0; u < 4; ++u) op[u << 12] = acc[u];
}

extern "C" void kernel_launch(void* const* d_in, const int* in_sizes, int n_in,
                              void* d_out, int out_size, void* d_ws, size_t ws_size,
                              hipStream_t stream) {
    const float* x   = (const float*)d_in[0];
    const float* w1  = (const float*)d_in[1];
    const float* b1  = (const float*)d_in[2];
    const float* a1  = (const float*)d_in[3];
    const float* wr  = (const float*)d_in[4];
    const float* br  = (const float*)d_in[5];
    const float* ws_ = (const float*)d_in[6];
    const float* bs  = (const float*)d_in[7];
    const float* a2  = (const float*)d_in[8];
    const float* w2  = (const float*)d_in[9];
    const float* b2  = (const float*)d_in[10];
    const float* wa  = (const float*)d_in[11];
    const float* ba  = (const float*)d_in[12];
    const float* wp1 = (const float*)d_in[13];
    const float* bp1 = (const float*)d_in[14];
    const float* ap  = (const float*)d_in[15];
    const float* wp2 = (const float*)d_in[16];
    const float* bp2 = (const float*)d_in[17];
    float* out = (float*)d_out;

    float* w = (float*)d_ws;
    float* ws_x1   = w;                        // 2*64*HW_
    float* ws_f    = ws_x1 + 2 * 64 * HW_;     // 2*32*HW_
    float* ws_x2   = ws_f  + 2 * 32 * HW_;     // 2*64*HW_
    float* ws_zp   = ws_x2 + 2 * 64 * HW_;     // 2*2*HW_
    float* ws_attn = ws_zp + 2 * 2 * HW_;      // NPX
    float* ws_p1   = ws_attn + NPX;            // 2*32*HW_

    hipLaunchKernelGGL(k_conv1, dim3(16 * NPG / 256), dim3(256), 0, stream,
                       x, w1, b1, a1, ws_x1);
    hipLaunchKernelGGL(k_reduce, dim3(8 * 16384 / 256), dim3(256), 0, stream,
                       ws_x1, wr, br, ws_f);
    hipLaunchKernelGGL(k_invol, dim3(512), dim3(256), 0, stream,
                       ws_x1, ws_f, ws_, bs, ws_x2, ws_zp);
    hipLaunchKernelGGL(k_attn, dim3(128), dim3(256), 0, stream,
                       ws_zp, wa, ba, ws_attn);
    hipLaunchKernelGGL(k_psec1, dim3(256), dim3(256), 0, stream,
                       ws_f, wp1, bp1, ap, ws_p1);
    hipLaunchKernelGGL(k_final, dim3(32 * NPG / 256), dim3(256), 0, stream,
                       ws_x2, ws_p1, ws_attn, a2, w2, b2, wp2, bp2, out);
}

// Round 8
// 194.505 us; speedup vs baseline: 1.8827x; 1.0775x over previous
//
#include <hip/hip_runtime.h>

#define HW_  16384   // H*W = 128*128
#define NPX  32768   // B*H*W

__device__ __forceinline__ float prelu_(float x, float a) { return x >= 0.f ? x : a * x; }

// ---------------- K1: x1 = prelu(conv1x1(x, w1, b1), a1) ----------------
// LDS-slab GEMM: block = 128 px x 32 outs (2 out-splits). w1^T in LDS (stride
// 36); x staged in two 64-ch half-K slabs (32 KB buffer). Thread = 4 px x 4 outs.
__global__ __launch_bounds__(256, 2) void k_conv1(const float* __restrict__ x,
        const float* __restrict__ w1, const float* __restrict__ b1,
        const float* __restrict__ a1p, float* __restrict__ x1) {
    __shared__ float xs[64 * 128];     // 32 KB: [ch-half][px]
    __shared__ float wT[128 * 36];     // 18 KB: [c][o] stride 36 (b128-aligned)
    int split = blockIdx.x >> 8;       // 0..1, block-uniform
    int tile = blockIdx.x & 255;
    int b = tile >> 7;
    int hw0 = (tile & 127) << 7;       // 128 px per block
    int o0 = split * 32;

    for (int e = threadIdx.x; e < 4096; e += 256) {      // coalesced w1 read
        int o = e >> 7, c = e & 127;
        wT[c * 36 + o] = w1[(o0 + o) * 128 + c];
    }
    int pxq = threadIdx.x & 31, outq = threadIdx.x >> 5; // 32 px-quads x 8 out-quads
    const float a1 = a1p[0];
    float4 acc[4];
    #pragma unroll
    for (int u = 0; u < 4; ++u) { float bv = b1[o0 + outq * 4 + u]; acc[u] = make_float4(bv, bv, bv, bv); }
    const float4* xb = (const float4*)(x + (b << 21) + hw0);   // ch stride 4096 f4
    #pragma unroll 1
    for (int half = 0; half < 2; ++half) {
        float4 xv[8];
        #pragma unroll
        for (int i = 0; i < 8; ++i) {
            int e = threadIdx.x + i * 256;               // e = ch*32 + pq
            int ch = e >> 5, pq = e & 31;
            xv[i] = xb[((half * 64 + ch) << 12) + pq];
        }
        #pragma unroll
        for (int i = 0; i < 8; ++i) {
            int e = threadIdx.x + i * 256;
            int ch = e >> 5, pq = e & 31;
            *(float4*)&xs[ch * 128 + pq * 4] = xv[i];
        }
        __syncthreads();
        #pragma unroll 8
        for (int c2 = 0; c2 < 64; ++c2) {
            float4 tap = *(const float4*)&xs[c2 * 128 + pxq * 4];
            float4 wv  = *(const float4*)&wT[(half * 64 + c2) * 36 + outq * 4];
            acc[0].x = fmaf(wv.x, tap.x, acc[0].x); acc[0].y = fmaf(wv.x, tap.y, acc[0].y);
            acc[0].z = fmaf(wv.x, tap.z, acc[0].z); acc[0].w = fmaf(wv.x, tap.w, acc[0].w);
            acc[1].x = fmaf(wv.y, tap.x, acc[1].x); acc[1].y = fmaf(wv.y, tap.y, acc[1].y);
            acc[1].z = fmaf(wv.y, tap.z, acc[1].z); acc[1].w = fmaf(wv.y, tap.w, acc[1].w);
            acc[2].x = fmaf(wv.z, tap.x, acc[2].x); acc[2].y = fmaf(wv.z, tap.y, acc[2].y);
            acc[2].z = fmaf(wv.z, tap.z, acc[2].z); acc[2].w = fmaf(wv.z, tap.w, acc[2].w);
            acc[3].x = fmaf(wv.w, tap.x, acc[3].x); acc[3].y = fmaf(wv.w, tap.y, acc[3].y);
            acc[3].z = fmaf(wv.w, tap.z, acc[3].z); acc[3].w = fmaf(wv.w, tap.w, acc[3].w);
        }
        __syncthreads();
    }
    #pragma unroll
    for (int u = 0; u < 4; ++u) {
        float4 r;
        r.x = prelu_(acc[u].x, a1); r.y = prelu_(acc[u].y, a1);
        r.z = prelu_(acc[u].z, a1); r.w = prelu_(acc[u].w, a1);
        *(float4*)(x1 + ((b * 64 + o0 + outq * 4 + u) << 14) + hw0 + pxq * 4) = r;
    }
}

// ---------------- K2: f = relu(conv1x1(x1, wr, br)) ----------------
// 8 splits x 4 out/thread x 2 px/thread (float2); 16-deep load batches.
__global__ __launch_bounds__(256, 4) void k_reduce(const float* __restrict__ x1,
        const float* __restrict__ wr, const float* __restrict__ br,
        float* __restrict__ f) {
    int tid = blockIdx.x * 256 + threadIdx.x;
    int p2 = tid & 16383;            // global px-pair 0..16383
    int q = tid >> 14;               // 0..7, block-uniform
    int b = p2 >> 13;
    int hw = (p2 & 8191) << 1;
    int o0 = q * 4;
    float2 acc[4];
    #pragma unroll
    for (int u = 0; u < 4; ++u) { float bv = br[o0 + u]; acc[u] = make_float2(bv, bv); }
    const float2* xp = (const float2*)(x1 + (b << 20) + hw);  // ch stride 8192 float2
    #pragma unroll 1
    for (int cb = 0; cb < 4; ++cb) {
        float2 xv[16];
        #pragma unroll
        for (int j = 0; j < 16; ++j) xv[j] = xp[(cb * 16 + j) << 13];
        #pragma unroll
        for (int j = 0; j < 16; ++j) {
            int c = cb * 16 + j;
            #pragma unroll
            for (int u = 0; u < 4; ++u) {
                float wv = wr[(o0 + u) * 64 + c];
                acc[u].x = fmaf(wv, xv[j].x, acc[u].x);
                acc[u].y = fmaf(wv, xv[j].y, acc[u].y);
            }
        }
    }
    float2* op = (float2*)(f + (b << 19) + hw);
    #pragma unroll
    for (int u = 0; u < 4; ++u) {
        float2 r;
        r.x = fmaxf(acc[u].x, 0.f); r.y = fmaxf(acc[u].y, 0.f);
        op[(o0 + u) << 13] = r;
    }
}

// ---------------- K3: fused span conv + involution -> x2 (+ ZPool on g==0) ----
__global__ __launch_bounds__(256) void k_invol(const float* __restrict__ x1,
        const float* __restrict__ f, const float* __restrict__ ws_,
        const float* __restrict__ bs, float* __restrict__ x2,
        float* __restrict__ zp) {
    __shared__ float tile[16 * 22 * 24];   // [c][r][col], rowstride 24 (2-way alias = free)
    int g = blockIdx.x >> 7;               // 0..3, block-uniform
    int t = blockIdx.x & 127;              // b*64 + tile id
    int b = t >> 6;
    int th = (t >> 3) & 7, tw = t & 7;
    int h0 = th * 16, w0 = tw * 16;
    const float* x1g = x1 + ((b * 64 + g * 16) << 14);
    #pragma unroll 1
    for (int rem = threadIdx.x; rem < 484; rem += 256) {
        int r = rem / 22, cl = rem - r * 22;
        int hh = h0 + r - 3, ww = w0 + cl - 3;
        bool ok = (hh >= 0 && hh < 128 && ww >= 0 && ww < 128);
        const float* src = x1g + (hh << 7) + ww;
        float v[16];
        #pragma unroll
        for (int c = 0; c < 16; ++c) v[c] = ok ? src[c << 14] : 0.f;
        float* dst = tile + r * 24 + cl;
        #pragma unroll
        for (int c = 0; c < 16; ++c) dst[c * 528] = v[c];
    }
    int lh = threadIdx.x >> 4, lw = threadIdx.x & 15;
    int hw = ((h0 + lh) << 7) + w0 + lw;
    float fv[32];
    const float* fp = f + (b << 19) + hw;
    #pragma unroll
    for (int c = 0; c < 32; ++c) fv[c] = fp[c << 14];
    if (g == 0) {                          // block-uniform: free ZPool
        float mx = fv[0], sm = fv[0];
        #pragma unroll
        for (int c = 1; c < 32; ++c) { mx = fmaxf(mx, fv[c]); sm += fv[c]; }
        zp[((b * 2 + 0) << 14) + hw] = mx;
        zp[((b * 2 + 1) << 14) + hw] = sm * (1.f / 32.f);
    }
    __syncthreads();
    float acc[16];
    #pragma unroll
    for (int u = 0; u < 16; ++u) acc[u] = 0.f;
    const float* tap0 = tile + lh * 24 + lw;
    const float* wk = ws_ + g * 49 * 32;
    const float* bsg = bs + g * 49;
    #pragma unroll 1
    for (int di = 0; di < 7; ++di) {
        #pragma unroll 1
        for (int dj = 0; dj < 7; ++dj) {
            int kk = di * 7 + dj;
            float kwv = bsg[kk];
            const float* wkk = wk + kk * 32;
            #pragma unroll
            for (int c = 0; c < 32; ++c) kwv = fmaf(wkk[c], fv[c], kwv);
            const float* tp = tap0 + di * 24 + dj;
            #pragma unroll
            for (int u = 0; u < 16; ++u)
                acc[u] = fmaf(kwv, tp[u * 528], acc[u]);
        }
    }
    float* op = x2 + ((b * 64 + g * 16) << 14) + hw;
    #pragma unroll
    for (int u = 0; u < 16; ++u) op[u << 14] = acc[u];
}

// ---------------- K4: attn = sigmoid(conv7x7(zp, wa, ba)) ----------------
__global__ __launch_bounds__(256) void k_attn(const float* __restrict__ zp,
        const float* __restrict__ wa, const float* __restrict__ ba,
        float* __restrict__ attn) {
    __shared__ float zs[2][22 * 23];       // stride 23
    int t = blockIdx.x;                    // 0..127
    int b = t >> 6;
    int tile = t & 63;
    int th = tile >> 3, tw = tile & 7;
    int h0 = th * 16, w0 = tw * 16;
    const float* zb = zp + (b << 15);      // b*2*HW_
    #pragma unroll 1
    for (int rem = threadIdx.x; rem < 484; rem += 256) {
        int r = rem / 22, cl = rem - r * 22;
        int hh = h0 + r - 3, ww = w0 + cl - 3;
        bool ok = (hh >= 0 && hh < 128 && ww >= 0 && ww < 128);
        const float* src = zb + (hh << 7) + ww;
        float v0 = ok ? src[0] : 0.f;
        float v1 = ok ? src[HW_] : 0.f;
        zs[0][r * 23 + cl] = v0;
        zs[1][r * 23 + cl] = v1;
    }
    __syncthreads();
    int lh = threadIdx.x >> 4, lw = threadIdx.x & 15;
    float acc = ba[0];
    #pragma unroll
    for (int c = 0; c < 2; ++c) {
        const float* zc = &zs[c][lh * 23 + lw];
        #pragma unroll
        for (int i = 0; i < 7; ++i)
            #pragma unroll
            for (int j = 0; j < 7; ++j)
                acc = fmaf(wa[c * 49 + i * 7 + j], zc[i * 23 + j], acc);
    }
    attn[(b << 14) + ((h0 + lh) << 7) + w0 + lw] = 1.f / (1.f + expf(-acc));
}

// ---------------- K5: p1 = prelu(conv3x3(f, wp1, bp1), ap) ----------------
// Block = 8x16 px tile x 16 outs (2 halves): 512 blocks, 42.7 KB LDS (2/CU).
// Thread = 4 px x 2 outs.
__global__ __launch_bounds__(256) void k_psec1(const float* __restrict__ f,
        const float* __restrict__ wp1, const float* __restrict__ bp1,
        const float* __restrict__ app, float* __restrict__ p1) {
    __shared__ float fs[32 * 190];         // 24320 B: [ci][r(10)][cl(<=18)] stride 19
    __shared__ float wT[288 * 16];         // 18432 B
    int half = blockIdx.x >> 8;            // 0..1, block-uniform
    int t = blockIdx.x & 255;
    int b = t >> 7;
    int tile = t & 127;                    // 16 h-tiles x 8 w-tiles
    int th = tile >> 3, tw = tile & 7;
    int h0 = th * 8, w0 = tw * 16;
    int o0 = half * 16;

    const float4* wsrc4 = (const float4*)(wp1 + o0 * 288);   // 72 float4 per o
    #pragma unroll 1
    for (int e4 = threadIdx.x; e4 < 1152; e4 += 256) {
        float4 v = wsrc4[e4];
        int o = e4 / 72, r4 = (e4 - o * 72) * 4;
        wT[(r4 + 0) * 16 + o] = v.x;
        wT[(r4 + 1) * 16 + o] = v.y;
        wT[(r4 + 2) * 16 + o] = v.z;
        wT[(r4 + 3) * 16 + o] = v.w;
    }
    const float* fb = f + (b << 19);
    #pragma unroll 1
    for (int rem = threadIdx.x; rem < 180; rem += 256) {
        int r = rem / 18, cl = rem - r * 18;
        int hh = h0 + r - 1, ww = w0 + cl - 1;
        bool ok = (hh >= 0 && hh < 128 && ww >= 0 && ww < 128);
        const float* src = fb + (hh << 7) + ww;
        float* dst = fs + r * 19 + cl;
        #pragma unroll 1
        for (int cb = 0; cb < 4; ++cb) {
            float v[8];
            #pragma unroll
            for (int c = 0; c < 8; ++c) v[c] = ok ? src[(cb * 8 + c) << 14] : 0.f;
            #pragma unroll
            for (int c = 0; c < 8; ++c) dst[(cb * 8 + c) * 190] = v[c];
        }
    }
    __syncthreads();

    int pxq = threadIdx.x & 31;            // 32 px-quads cover 128 px
    int rowq = pxq >> 2, colq = pxq & 3;   // row 0..7, col-quad 0..3
    int oh = threadIdx.x >> 5;             // 0..7 -> outs o0+oh*2, +1
    const float ap = app[0];
    float acc[2][4];
    #pragma unroll
    for (int o = 0; o < 2; ++o) {
        float bv = bp1[o0 + oh * 2 + o];
        #pragma unroll
        for (int px = 0; px < 4; ++px) acc[o][px] = bv;
    }
    const float* fsb = fs + rowq * 19 + colq * 4;
    for (int ci = 0; ci < 32; ++ci) {
        float tap[3][6];
        const float* base = fsb + ci * 190;
        #pragma unroll
        for (int r = 0; r < 3; ++r)
            #pragma unroll
            for (int j = 0; j < 6; ++j)
                tap[r][j] = base[r * 19 + j];
        #pragma unroll
        for (int ki = 0; ki < 3; ++ki)
            #pragma unroll
            for (int kj = 0; kj < 3; ++kj) {
                float2 wv = *(const float2*)&wT[((ci * 9 + ki * 3 + kj) << 4) + oh * 2];
                #pragma unroll
                for (int px = 0; px < 4; ++px) {
                    float tv = tap[ki][px + kj];
                    acc[0][px] = fmaf(wv.x, tv, acc[0][px]);
                    acc[1][px] = fmaf(wv.y, tv, acc[1][px]);
                }
            }
    }
    int hw = ((h0 + rowq) << 7) + w0 + colq * 4;
    #pragma unroll
    for (int o = 0; o < 2; ++o) {
        float4 r;
        r.x = prelu_(acc[o][0], ap); r.y = prelu_(acc[o][1], ap);
        r.z = prelu_(acc[o][2], ap); r.w = prelu_(acc[o][3], ap);
        *(float4*)(p1 + ((b * 32 + o0 + oh * 2 + o) << 14) + hw) = r;
    }
}

// ---------------- K6: out = conv2(prelu(x2,a2))*attn + (wp2·p1+bp2) --------
// LDS-slab GEMM: block = 128 px x 32 outs (4 splits). prelu(x2), p1, attn and
// both weight mats staged in LDS (62 KB, 2/CU). Thread = 4 px x 4 outs.
__global__ __launch_bounds__(256, 2) void k_final(const float* __restrict__ x2,
        const float* __restrict__ p1, const float* __restrict__ attn,
        const float* __restrict__ a2p, const float* __restrict__ w2,
        const float* __restrict__ b2, const float* __restrict__ wp2,
        const float* __restrict__ bp2, float* __restrict__ out) {
    __shared__ float xs2[64 * 128];    // 32 KB prelu(x2)
    __shared__ float ps[32 * 128];     // 16 KB p1
    __shared__ float wT2[64 * 36];     // 9216 B
    __shared__ float wTp[32 * 36];     // 4608 B
    __shared__ float as_[128];         // attn tile
    int split = blockIdx.x >> 8;       // 0..3, block-uniform
    int tile = blockIdx.x & 255;
    int b = tile >> 7;
    int hw0 = (tile & 127) << 7;
    int o0 = split * 32;
    const float a2 = a2p[0];

    for (int e = threadIdx.x; e < 2048; e += 256) {      // w2 coalesced
        int o = e >> 6, c = e & 63;
        wT2[c * 36 + o] = w2[(o0 + o) * 64 + c];
    }
    for (int e = threadIdx.x; e < 1024; e += 256) {      // wp2 coalesced
        int o = e >> 5, c = e & 31;
        wTp[c * 36 + o] = wp2[(o0 + o) * 32 + c];
    }
    {
        const float4* xb = (const float4*)(x2 + (b << 20) + hw0);
        float4 xv[8];
        #pragma unroll
        for (int i = 0; i < 8; ++i) {
            int e = threadIdx.x + i * 256;
            xv[i] = xb[((e >> 5) << 12) + (e & 31)];
        }
        #pragma unroll
        for (int i = 0; i < 8; ++i) {
            int e = threadIdx.x + i * 256;
            float4 v = xv[i];
            v.x = prelu_(v.x, a2); v.y = prelu_(v.y, a2);
            v.z = prelu_(v.z, a2); v.w = prelu_(v.w, a2);
            *(float4*)&xs2[(e >> 5) * 128 + (e & 31) * 4] = v;
        }
        const float4* pb = (const float4*)(p1 + (b << 19) + hw0);
        float4 pv[4];
        #pragma unroll
        for (int i = 0; i < 4; ++i) {
            int e = threadIdx.x + i * 256;
            pv[i] = pb[((e >> 5) << 12) + (e & 31)];
        }
        #pragma unroll
        for (int i = 0; i < 4; ++i) {
            int e = threadIdx.x + i * 256;
            *(float4*)&ps[(e >> 5) * 128 + (e & 31) * 4] = pv[i];
        }
        if (threadIdx.x < 32)
            ((float4*)as_)[threadIdx.x] = ((const float4*)(attn + (b << 14) + hw0))[threadIdx.x];
    }
    int pxq = threadIdx.x & 31, outq = threadIdx.x >> 5;
    float b2v[4], bpv[4];
    #pragma unroll
    for (int u = 0; u < 4; ++u) { b2v[u] = b2[o0 + outq * 4 + u]; bpv[u] = bp2[o0 + outq * 4 + u]; }
    __syncthreads();

    float4 acc[4];
    #pragma unroll
    for (int u = 0; u < 4; ++u) acc[u] = make_float4(0.f, 0.f, 0.f, 0.f);
    #pragma unroll 8
    for (int c = 0; c < 64; ++c) {
        float4 tap = *(const float4*)&xs2[c * 128 + pxq * 4];
        float4 wv  = *(const float4*)&wT2[c * 36 + outq * 4];
        acc[0].x = fmaf(wv.x, tap.x, acc[0].x); acc[0].y = fmaf(wv.x, tap.y, acc[0].y);
        acc[0].z = fmaf(wv.x, tap.z, acc[0].z); acc[0].w = fmaf(wv.x, tap.w, acc[0].w);
        acc[1].x = fmaf(wv.y, tap.x, acc[1].x); acc[1].y = fmaf(wv.y, tap.y, acc[1].y);
        acc[1].z = fmaf(wv.y, tap.z, acc[1].z); acc[1].w = fmaf(wv.y, tap.w, acc[1].w);
        acc[2].x = fmaf(wv.z, tap.x, acc[2].x); acc[2].y = fmaf(wv.z, tap.y, acc[2].y);
        acc[2].z = fmaf(wv.z, tap.z, acc[2].z); acc[2].w = fmaf(wv.z, tap.w, acc[2].w);
        acc[3].x = fmaf(wv.w, tap.x, acc[3].x); acc[3].y = fmaf(wv.w, tap.y, acc[3].y);
        acc[3].z = fmaf(wv.w, tap.z, acc[3].z); acc[3].w = fmaf(wv.w, tap.w, acc[3].w);
    }
    float4 at = *(const float4*)&as_[pxq * 4];
    #pragma unroll
    for (int u = 0; u < 4; ++u) {
        acc[u].x = (acc[u].x + b2v[u]) * at.x + bpv[u];
        acc[u].y = (acc[u].y + b2v[u]) * at.y + bpv[u];
        acc[u].z = (acc[u].z + b2v[u]) * at.z + bpv[u];
        acc[u].w = (acc[u].w + b2v[u]) * at.w + bpv[u];
    }
    #pragma unroll 8
    for (int c = 0; c < 32; ++c) {
        float4 tap = *(const float4*)&ps[c * 128 + pxq * 4];
        float4 wv  = *(const float4*)&wTp[c * 36 + outq * 4];
        acc[0].x = fmaf(wv.x, tap.x, acc[0].x); acc[0].y = fmaf(wv.x, tap.y, acc[0].y);
        acc[0].z = fmaf(wv.x, tap.z, acc[0].z); acc[0].w = fmaf(wv.x, tap.w, acc[0].w);
        acc[1].x = fmaf(wv.y, tap.x, acc[1].x); acc[1].y = fmaf(wv.y, tap.y, acc[1].y);
        acc[1].z = fmaf(wv.y, tap.z, acc[1].z); acc[1].w = fmaf(wv.y, tap.w, acc[1].w);
        acc[2].x = fmaf(wv.z, tap.x, acc[2].x); acc[2].y = fmaf(wv.z, tap.y, acc[2].y);
        acc[2].z = fmaf(wv.z, tap.z, acc[2].z); acc[2].w = fmaf(wv.z, tap.w, acc[2].w);
        acc[3].x = fmaf(wv.w, tap.x, acc[3].x); acc[3].y = fmaf(wv.w, tap.y, acc[3].y);
        acc[3].z = fmaf(wv.w, tap.z, acc[3].z); acc[3].w = fmaf(wv.w, tap.w, acc[3].w);
    }
    #pragma unroll
    for (int u = 0; u < 4; ++u)
        *(float4*)(out + ((b * 128 + o0 + outq * 4 + u) << 14) + hw0 + pxq * 4) = acc[u];
}

extern "C" void kernel_launch(void* const* d_in, const int* in_sizes, int n_in,
                              void* d_out, int out_size, void* d_ws, size_t ws_size,
                              hipStream_t stream) {
    const float* x   = (const float*)d_in[0];
    const float* w1  = (const float*)d_in[1];
    const float* b1  = (const float*)d_in[2];
    const float* a1  = (const float*)d_in[3];
    const float* wr  = (const float*)d_in[4];
    const float* br  = (const float*)d_in[5];
    const float* ws_ = (const float*)d_in[6];
    const float* bs  = (const float*)d_in[7];
    const float* a2  = (const float*)d_in[8];
    const float* w2  = (const float*)d_in[9];
    const float* b2  = (const float*)d_in[10];
    const float* wa  = (const float*)d_in[11];
    const float* ba  = (const float*)d_in[12];
    const float* wp1 = (const float*)d_in[13];
    const float* bp1 = (const float*)d_in[14];
    const float* ap  = (const float*)d_in[15];
    const float* wp2 = (const float*)d_in[16];
    const float* bp2 = (const float*)d_in[17];
    float* out = (float*)d_out;

    float* w = (float*)d_ws;
    float* ws_x1   = w;                        // 2*64*HW_
    float* ws_f    = ws_x1 + 2 * 64 * HW_;     // 2*32*HW_
    float* ws_x2   = ws_f  + 2 * 32 * HW_;     // 2*64*HW_
    float* ws_zp   = ws_x2 + 2 * 64 * HW_;     // 2*2*HW_
    float* ws_attn = ws_zp + 2 * 2 * HW_;      // NPX
    float* ws_p1   = ws_attn + NPX;            // 2*32*HW_

    hipLaunchKernelGGL(k_conv1, dim3(512), dim3(256), 0, stream,
                       x, w1, b1, a1, ws_x1);
    hipLaunchKernelGGL(k_reduce, dim3(8 * 16384 / 256), dim3(256), 0, stream,
                       ws_x1, wr, br, ws_f);
    hipLaunchKernelGGL(k_invol, dim3(512), dim3(256), 0, stream,
                       ws_x1, ws_f, ws_, bs, ws_x2, ws_zp);
    hipLaunchKernelGGL(k_attn, dim3(128), dim3(256), 0, stream,
                       ws_zp, wa, ba, ws_attn);
    hipLaunchKernelGGL(k_psec1, dim3(512), dim3(256), 0, stream,
                       ws_f, wp1, bp1, ap, ws_p1);
    hipLaunchKernelGGL(k_final, dim3(1024), dim3(256), 0, stream,
                       ws_x2, ws_p1, ws_attn, a2, w2, b2, wp2, bp2, out);
}